// Round 8
// baseline (383.064 us; speedup 1.0000x reference)
//
#include <hip/hip_runtime.h>
#include <math.h>

#define NHEAD 8
#define DKD 64
#define DMODEL 512
#define LSEQ 1024
#define NBL 8192          // B*L

typedef __attribute__((ext_vector_type(8))) short bf8;   // 8 x bf16 (4 VGPRs)
typedef __attribute__((ext_vector_type(4))) float f4;    // MFMA accumulator

__device__ inline unsigned short f2bf(float f) {
    union { float f; unsigned u; } v; v.f = f;
    unsigned r = v.u + 0x7FFFu + ((v.u >> 16) & 1u);   // RNE
    return (unsigned short)(r >> 16);
}

// v_cvt_pk_bf16_f32: pack two fp32 -> two bf16 in one u32 (T12 recipe)
__device__ __forceinline__ unsigned cvtpk(float lo, float hi) {
    unsigned r;
    asm("v_cvt_pk_bf16_f32 %0, %1, %2" : "=v"(r) : "v"(lo), "v"(hi));
    return r;
}

// async global->LDS, 16B per lane. LDS dest = wave-uniform base + lane*16.
__device__ __forceinline__ void gload16(const void* g, void* l) {
    __builtin_amdgcn_global_load_lds(
        (const __attribute__((address_space(1))) unsigned int*)g,
        (__attribute__((address_space(3))) unsigned int*)l, 16, 0, 0);
}

// ---------------------------------------------------------------------------
// prepass: fp32 -> bf16 elementwise (x)
// ---------------------------------------------------------------------------
__global__ __launch_bounds__(256) void conv_bf16(
    const float* __restrict__ in, unsigned short* __restrict__ out, int n)
{
    int i = (blockIdx.x * 256 + threadIdx.x) * 4;
    if (i >= n) return;
    float4 v = *(const float4*)(in + i);
    ushort4 o;
    o.x = f2bf(v.x); o.y = f2bf(v.y); o.z = f2bf(v.z); o.w = f2bf(v.w);
    *(ushort4*)(out + i) = o;
}

// ---------------------------------------------------------------------------
// prepass: all weight transposes + bias concat in ONE launch (769 blocks)
// ---------------------------------------------------------------------------
__device__ __forceinline__ void do_transpose(
    const float* __restrict__ W, unsigned short* __restrict__ Wt,
    int K, int N, int bx, int by)
{
    __shared__ float tile[64][65];
    const int k0 = by * 64, n0 = bx * 64;
    const int c = threadIdx.x & 63, r0 = (threadIdx.x >> 6) * 16;
    #pragma unroll
    for (int i = 0; i < 16; ++i)
        tile[r0 + i][c] = W[(size_t)(k0 + r0 + i) * N + n0 + c];
    __syncthreads();
    #pragma unroll
    for (int i = 0; i < 16; ++i)
        Wt[(size_t)(n0 + r0 + i) * K + k0 + c] = f2bf(tile[c][r0 + i]);
}

__global__ __launch_bounds__(256) void prep_weights(
    const float* __restrict__ Wq, const float* __restrict__ Wk,
    const float* __restrict__ Wv, const float* __restrict__ Wo,
    const float* __restrict__ W1, const float* __restrict__ W2,
    const float* __restrict__ bq, const float* __restrict__ bk,
    const float* __restrict__ bv,
    unsigned short* __restrict__ Wqkv, unsigned short* __restrict__ Wot,
    unsigned short* __restrict__ W1t, unsigned short* __restrict__ W2t,
    float* __restrict__ bqkv)
{
    int j = blockIdx.x;
    if (j < 256) {                               // four 512x512 transposes
        int which = j >> 6, tt = j & 63;
        const float* src = which == 0 ? Wq : which == 1 ? Wk : which == 2 ? Wv : Wo;
        unsigned short* dst = which == 0 ? Wqkv : which == 1 ? (Wqkv + 262144)
                            : which == 2 ? (Wqkv + 524288) : Wot;
        do_transpose(src, dst, 512, 512, tt & 7, tt >> 3);
    } else if (j < 512) {                        // W1: [512,2048]
        int tt = j - 256;
        do_transpose(W1, W1t, 512, 2048, tt & 31, tt >> 5);
    } else if (j < 768) {                        // W2: [2048,512]
        int tt = j - 512;
        do_transpose(W2, W2t, 2048, 512, tt & 7, tt >> 3);
    } else {                                     // concat qkv biases
        for (int c = threadIdx.x; c < 1536; c += 256)
            bqkv[c] = c < 512 ? bq[c] : c < 1024 ? bk[c - 512] : bv[c - 1024];
    }
}

// ---------------------------------------------------------------------------
// bf16 MFMA GEMM: C[M,N] = A[M,K] @ Bt[N,K]^T + bias. Tile 128 x BN, 4 waves.
// BK=64; DOUBLE-BUFFERED LDS: stage(next) -> compute(cur) -> 1 barrier/step.
// global_load_lds (16B) with pre-swizzled source chunk; linear LDS;
// XOR-swizzled reads -> conflict-free ds_read_b128.
// outmode: 0 = fp32 [M,N] (+resid), 1 = bf16 [M,N] (+relu), 2 = QKV scatter
// ---------------------------------------------------------------------------
template<int BN>
__global__ __launch_bounds__(256) void mfma_gemm(
    const unsigned short* __restrict__ A, const unsigned short* __restrict__ Bt,
    const float* __restrict__ bias, const float* __restrict__ resid,
    void* __restrict__ outp, int M, int N, int K, int relu, int outmode,
    unsigned short* __restrict__ qs, unsigned short* __restrict__ ks,
    unsigned short* __restrict__ vts)
{
    __shared__ uint4 As[2][1024];       // [buf][128 rows x 8 chunks]
    __shared__ uint4 Bs[2][BN * 8];
    constexpr int NB = BN / 32;         // acc cols per wave

    const int t = threadIdx.x;
    const int lane = t & 63, w = t >> 6;
    const int g = lane >> 4, r15 = lane & 15;
    const int wr = w >> 1, wc = w & 1;
    const int rowBase = blockIdx.y * 128, colBase = blockIdx.x * BN;

    f4 acc[4][NB] = {};

    const int r   = t >> 3;                    // w*8 + (lane>>3)
    const int chs = (t & 7) ^ (r & 7);         // pre-swizzled source chunk
    const unsigned short* Ag0 = A  + (size_t)(rowBase + r) * K + chs * 8;
    const unsigned short* Bg0 = Bt + (size_t)(colBase + r) * K + chs * 8;

    auto stage = [&](int buf, int k0) {
        unsigned short* Al = (unsigned short*)As[buf] + (w * 8) * 64;
        unsigned short* Bl = (unsigned short*)Bs[buf] + (w * 8) * 64;
        const unsigned short* Ag = Ag0 + k0;
        const unsigned short* Bg = Bg0 + k0;
        #pragma unroll
        for (int p = 0; p < 4; ++p)
            gload16(Ag + (size_t)(p * 32) * K, Al + p * 32 * 64);
        #pragma unroll
        for (int p = 0; p < NB; ++p)
            gload16(Bg + (size_t)(p * 32) * K, Bl + p * 32 * 64);
    };

    const int nst = K >> 6;
    stage(0, 0);
    __syncthreads();

    for (int it = 0; it < nst; ++it) {
        const int cur = it & 1;
        if (it + 1 < nst) stage(cur ^ 1, (it + 1) << 6);
        #pragma unroll
        for (int kk = 0; kk < 2; ++kk) {
            bf8 af[4], bfr[NB];
            #pragma unroll
            for (int m = 0; m < 4; ++m) {
                int ra = wr * 64 + m * 16 + r15;
                af[m] = *(const bf8*)&As[cur][ra * 8 + ((kk * 4 + g) ^ (ra & 7))];
            }
            #pragma unroll
            for (int n = 0; n < NB; ++n) {
                int rb = wc * (BN / 2) + n * 16 + r15;
                bfr[n] = *(const bf8*)&Bs[cur][rb * 8 + ((kk * 4 + g) ^ (rb & 7))];
            }
            #pragma unroll
            for (int m = 0; m < 4; ++m)
                #pragma unroll
                for (int n = 0; n < NB; ++n)
                    acc[m][n] = __builtin_amdgcn_mfma_f32_16x16x32_bf16(
                        af[m], bfr[n], acc[m][n], 0, 0, 0);
        }
        __syncthreads();
    }

    #pragma unroll
    for (int m = 0; m < 4; ++m) {
        #pragma unroll
        for (int n = 0; n < NB; ++n) {
            int col = colBase + wc * (BN / 2) + n * 16 + r15;
            float bv = bias[col];
            #pragma unroll
            for (int rr = 0; rr < 4; ++rr) {
                int row = rowBase + wr * 64 + m * 16 + g * 4 + rr;
                float v = acc[m][n][rr] + bv;
                if (relu) v = fmaxf(v, 0.f);
                if (outmode == 0) {
                    size_t idx = (size_t)row * N + col;
                    if (resid) v += resid[idx];
                    ((float*)outp)[idx] = v;
                } else if (outmode == 1) {
                    ((unsigned short*)outp)[(size_t)row * N + col] = f2bf(v);
                } else {
                    int sel = col >> 9, hd = col & 511;
                    int h = hd >> 6, dk = hd & 63;
                    int b = row >> 10, l = row & 1023;
                    unsigned short bw = f2bf(v);
                    size_t bh = (size_t)(b * NHEAD + h);
                    if (sel == 0)      qs[(bh * LSEQ + l) * DKD + dk] = bw;
                    else if (sel == 1) ks[(bh * LSEQ + l) * DKD + dk] = bw;
                    else               vts[(bh * DKD + dk) * LSEQ + l] = bw;
                }
            }
        }
    }
}

// ---------------------------------------------------------------------------
// Flash attention v4. Block = 128 q-rows of one (b,h), 4 waves x 32 rows.
// Swapped QK^T (lane owns one q-row). Double-buffered K/V via global_load_lds.
// Bias+mask REGISTER-PREFETCHED one tile ahead (named trA/trB sets, kt loop
// unrolled x2). Mask folded in-kernel. setprio(1) around MFMA clusters.
// ---------------------------------------------------------------------------
struct TileRegs { float4 b[2][4]; unsigned mk[4]; };

__device__ __forceinline__ void load_tile_regs(
    TileRegs& tr, const float* bR0, const float* bR1,
    const unsigned char* mrow, int key0, int g)
{
    #pragma unroll
    for (int m = 0; m < 4; ++m) {
        tr.b[0][m] = *(const float4*)(bR0 + key0 + m * 16 + g * 4);
        tr.b[1][m] = *(const float4*)(bR1 + key0 + m * 16 + g * 4);
        tr.mk[m]   = *(const unsigned*)(mrow + key0 + m * 16 + g * 4);
    }
}

__device__ __forceinline__ void attn_tile(
    const uint4* __restrict__ Kb, const uint4* __restrict__ Vb,
    const TileRegs& tr, bf8 (&qf)[2][2], f4 (&oacc)[2][4],
    float (&mrun)[2], float (&lsum)[2],
    unsigned short* Pw, int g, int r15)
{
    // S^T = K Q for both q-groups (K frags shared)
    f4 sacc[2][4] = {};
    __builtin_amdgcn_s_setprio(1);
    #pragma unroll
    for (int kk = 0; kk < 2; ++kk)
        #pragma unroll
        for (int m = 0; m < 4; ++m) {
            int row = m * 16 + r15;
            bf8 kf = *(const bf8*)&Kb[row * 8 + ((kk * 4 + g) ^ (row & 7))];
            sacc[0][m] = __builtin_amdgcn_mfma_f32_16x16x32_bf16(kf, qf[0][kk], sacc[0][m], 0, 0, 0);
            sacc[1][m] = __builtin_amdgcn_mfma_f32_16x16x32_bf16(kf, qf[1][kk], sacc[1][m], 0, 0, 0);
        }
    __builtin_amdgcn_s_setprio(0);

    // mask adds (shared across u)
    float madd[16];
    #pragma unroll
    for (int m = 0; m < 4; ++m) {
        unsigned mku = tr.mk[m];
        #pragma unroll
        for (int j = 0; j < 4; ++j)
            madd[m * 4 + j] = ((mku >> (8 * j)) & 0xffu) ? -1e30f : 0.f;
    }

    // softmax per q-group (per-lane over 16 keys + 2 shfl)
    #pragma unroll
    for (int u = 0; u < 2; ++u) {
        float s[16];
        float pmax = -1e30f;
        #pragma unroll
        for (int m = 0; m < 4; ++m) {
            const float* bvp = (const float*)&tr.b[u][m];
            #pragma unroll
            for (int j = 0; j < 4; ++j) {
                float sv = fmaf(sacc[u][m][j], 0.125f, bvp[j] + madd[m * 4 + j]);
                s[m * 4 + j] = sv;
                pmax = fmaxf(pmax, sv);
            }
        }
        pmax = fmaxf(pmax, __shfl_xor(pmax, 16));
        pmax = fmaxf(pmax, __shfl_xor(pmax, 32));

        if (!__all(pmax <= mrun[u] + 8.f)) {     // defer-max (T13)
            float mnew = fmaxf(mrun[u], pmax);
            float scale = __expf(mrun[u] - mnew);
            lsum[u] *= scale;
            #pragma unroll
            for (int m = 0; m < 4; ++m)
                #pragma unroll
                for (int j = 0; j < 4; ++j) oacc[u][m][j] *= scale;
            mrun[u] = mnew;
        }

        float psum = 0.f;
        #pragma unroll
        for (int i = 0; i < 16; ++i) { s[i] = __expf(s[i] - mrun[u]); psum += s[i]; }
        psum += __shfl_xor(psum, 16);
        psum += __shfl_xor(psum, 32);
        lsum[u] += psum;

        // pack P -> per-wave LDS (bf16, XOR-swizzled), wave-private
        #pragma unroll
        for (int m = 0; m < 4; ++m) {
            uint2 pk;
            pk.x = cvtpk(s[m * 4 + 0], s[m * 4 + 1]);
            pk.y = cvtpk(s[m * 4 + 2], s[m * 4 + 3]);
            int off = ((u * 16 + r15) * 128 + m * 32 + g * 8) ^ ((r15 & 7) << 4);
            *(uint2*)((char*)Pw + off) = pk;
        }
    }

    // O^T += V^T P (V frags shared across q-groups)
    #pragma unroll
    for (int kk = 0; kk < 2; ++kk) {
        bf8 pf[2];
        #pragma unroll
        for (int u = 0; u < 2; ++u) {
            int off = ((u * 16 + r15) * 128 + kk * 64 + g * 16) ^ ((r15 & 7) << 4);
            pf[u] = *(const bf8*)((char*)Pw + off);
        }
        __builtin_amdgcn_s_setprio(1);
        #pragma unroll
        for (int m = 0; m < 4; ++m) {
            int row = m * 16 + r15;
            bf8 vf = *(const bf8*)&Vb[row * 8 + ((kk * 4 + g) ^ (row & 7))];
            oacc[0][m] = __builtin_amdgcn_mfma_f32_16x16x32_bf16(vf, pf[0], oacc[0][m], 0, 0, 0);
            oacc[1][m] = __builtin_amdgcn_mfma_f32_16x16x32_bf16(vf, pf[1], oacc[1][m], 0, 0, 0);
        }
        __builtin_amdgcn_s_setprio(0);
    }
}

__global__ __launch_bounds__(256) void attn_mfma(
    const unsigned short* __restrict__ Qg, const unsigned short* __restrict__ Kg,
    const unsigned short* __restrict__ Vtg, const float* __restrict__ bias,
    const unsigned char* __restrict__ mask, unsigned short* __restrict__ Ob)
{
    __shared__ uint4 Ks[2][512];         // [buf][64 keys x 8 chunks]
    __shared__ uint4 Vs[2][512];         // [buf][64 dk x 8 key-chunks]
    __shared__ unsigned int Pb[4096];    // 4 waves x 32 rows x 64 keys bf16

    const int t = threadIdx.x;
    const int lane = t & 63, w = t >> 6;
    const int g = lane >> 4, r15 = lane & 15;

    // XCD-aware remap (512 blocks, 64 per XCD chunk)
    const int p = blockIdx.x;
    const int logical = (p & 7) * 64 + (p >> 3);
    const int bh = logical >> 3, qt = logical & 7;
    const int b = bh >> 3, h = bh & 7;
    const int qbase = qt * 128 + w * 32;

    bf8 qf[2][2];
    #pragma unroll
    for (int u = 0; u < 2; ++u) {
        const unsigned short* qp = Qg + ((size_t)bh * LSEQ + qbase + u * 16 + r15) * DKD + g * 8;
        qf[u][0] = *(const bf8*)qp;
        qf[u][1] = *(const bf8*)(qp + 32);
    }

    float mrun[2] = {-1e30f, -1e30f}, lsum[2] = {0.f, 0.f};
    f4 oacc[2][4] = {};

    const int sr  = t >> 3;                    // 0..31
    const int chs = (t & 7) ^ (sr & 7);        // pre-swizzled source chunk
    unsigned short* Pw = (unsigned short*)(Pb + w * 1024);

    const size_t kBase = (size_t)bh * LSEQ * DKD;   // K rows
    const size_t vBase = (size_t)bh * DKD * LSEQ;   // V^T rows

    const float* bR0 = bias + ((size_t)b << 20) + (size_t)(qbase + r15) * LSEQ;
    const float* bR1 = bias + ((size_t)b << 20) + (size_t)(qbase + 16 + r15) * LSEQ;
    const unsigned char* mrow = mask + b * LSEQ;

    auto stage = [&](uint4* Kbuf, uint4* Vbuf, int key0) {
        const unsigned short* Kgp = Kg  + kBase + (size_t)(key0 + sr) * DKD + chs * 8;
        const unsigned short* Vgp = Vtg + vBase + (size_t)sr * LSEQ + key0 + chs * 8;
        unsigned short* Kl = (unsigned short*)Kbuf + (w * 8) * 64;
        unsigned short* Vl = (unsigned short*)Vbuf + (w * 8) * 64;
        gload16(Kgp, Kl);
        gload16(Kgp + (size_t)32 * DKD, Kl + 32 * 64);
        gload16(Vgp, Vl);
        gload16(Vgp + (size_t)32 * LSEQ, Vl + 32 * 64);
    };

    TileRegs trA, trB;
    load_tile_regs(trA, bR0, bR1, mrow, 0, g);
    stage(Ks[0], Vs[0], 0);
    __syncthreads();

    for (int kt2 = 0; kt2 < 8; ++kt2) {
        const int keyE = kt2 * 128;
        // even tile (buf0, trA); prefetch odd tile into buf1/trB
        stage(Ks[1], Vs[1], keyE + 64);
        load_tile_regs(trB, bR0, bR1, mrow, keyE + 64, g);
        attn_tile(Ks[0], Vs[0], trA, qf, oacc, mrun, lsum, Pw, g, r15);
        __syncthreads();
        // odd tile (buf1, trB); prefetch next even into buf0/trA
        if (kt2 < 7) {
            stage(Ks[0], Vs[0], keyE + 128);
            load_tile_regs(trA, bR0, bR1, mrow, keyE + 128, g);
        }
        attn_tile(Ks[1], Vs[1], trB, qf, oacc, mrun, lsum, Pw, g, r15);
        __syncthreads();
    }

    #pragma unroll
    for (int u = 0; u < 2; ++u) {
        float inv = 1.f / lsum[u];
        unsigned short* op = Ob + ((size_t)b * LSEQ + qbase + u * 16 + r15) * DMODEL + h * DKD;
        #pragma unroll
        for (int m = 0; m < 4; ++m) {
            ushort4 o4;
            o4.x = f2bf(oacc[u][m][0] * inv);
            o4.y = f2bf(oacc[u][m][1] * inv);
            o4.z = f2bf(oacc[u][m][2] * inv);
            o4.w = f2bf(oacc[u][m][3] * inv);
            *(ushort4*)(op + m * 16 + g * 4) = o4;
        }
    }
}

// ---------------------------------------------------------------------------
// LayerNorm (fp32), optional bf16 secondary output. One wave per row of 512.
// ---------------------------------------------------------------------------
__global__ __launch_bounds__(256) void ln_kernel(
    const float* __restrict__ in, const float* __restrict__ g,
    const float* __restrict__ bt, float* __restrict__ out,
    unsigned short* __restrict__ outb)
{
    const int row  = blockIdx.x * 4 + (threadIdx.x >> 6);
    const int lane = threadIdx.x & 63;
    const float* rp = in + (size_t)row * DMODEL + lane * 8;
    float4 x0 = *(const float4*)rp;
    float4 x1 = *(const float4*)(rp + 4);
    float xs[8] = {x0.x, x0.y, x0.z, x0.w, x1.x, x1.y, x1.z, x1.w};

    float sum = 0.f;
    #pragma unroll
    for (int i = 0; i < 8; ++i) sum += xs[i];
    #pragma unroll
    for (int off = 32; off; off >>= 1) sum += __shfl_xor(sum, off);
    float mu = sum * (1.f / 512.f);

    float vs = 0.f;
    #pragma unroll
    for (int i = 0; i < 8; ++i) { float d = xs[i] - mu; vs += d * d; }
    #pragma unroll
    for (int off = 32; off; off >>= 1) vs += __shfl_xor(vs, off);
    float rs = rsqrtf(vs * (1.f / 512.f) + 1e-5f);

    const float* gp = g  + lane * 8;
    const float* bp = bt + lane * 8;
    float4 g0 = *(const float4*)gp, g1 = *(const float4*)(gp + 4);
    float4 b0 = *(const float4*)bp, b1 = *(const float4*)(bp + 4);
    float gs[8] = {g0.x, g0.y, g0.z, g0.w, g1.x, g1.y, g1.z, g1.w};
    float bs[8] = {b0.x, b0.y, b0.z, b0.w, b1.x, b1.y, b1.z, b1.w};

    float res[8];
    #pragma unroll
    for (int i = 0; i < 8; ++i) res[i] = (xs[i] - mu) * rs * gs[i] + bs[i];

    float* op = out + (size_t)row * DMODEL + lane * 8;
    float4 r0 = {res[0], res[1], res[2], res[3]};
    float4 r1 = {res[4], res[5], res[6], res[7]};
    *(float4*)op       = r0;
    *(float4*)(op + 4) = r1;

    if (outb) {
        unsigned short* ob = outb + (size_t)row * DMODEL + lane * 8;
        ushort4 u0, u1;
        u0.x = f2bf(res[0]); u0.y = f2bf(res[1]); u0.z = f2bf(res[2]); u0.w = f2bf(res[3]);
        u1.x = f2bf(res[4]); u1.y = f2bf(res[5]); u1.z = f2bf(res[6]); u1.w = f2bf(res[7]);
        *(ushort4*)ob       = u0;
        *(ushort4*)(ob + 4) = u1;
    }
}

// ---------------------------------------------------------------------------
extern "C" void kernel_launch(void* const* d_in, const int* in_sizes, int n_in,
                              void* d_out, int out_size, void* d_ws, size_t ws_size,
                              hipStream_t stream)
{
    const float*         x    = (const float*)d_in[0];
    const unsigned char* mask = (const unsigned char*)d_in[1];
    const float*         bias = (const float*)d_in[2];
    const float* Wq = (const float*)d_in[3];
    const float* bq = (const float*)d_in[4];
    const float* Wk = (const float*)d_in[5];
    const float* bk = (const float*)d_in[6];
    const float* Wv = (const float*)d_in[7];
    const float* bv = (const float*)d_in[8];
    const float* Wo = (const float*)d_in[9];
    const float* bo = (const float*)d_in[10];
    const float* ln1g = (const float*)d_in[11];
    const float* ln1b = (const float*)d_in[12];
    const float* W1 = (const float*)d_in[13];
    const float* b1 = (const float*)d_in[14];
    const float* W2 = (const float*)d_in[15];
    const float* b2 = (const float*)d_in[16];
    const float* ln2g = (const float*)d_in[17];
    const float* ln2b = (const float*)d_in[18];

    char* W = (char*)d_ws;
    unsigned short* Qb   = (unsigned short*)(W);                 // 8 MB   [dead after attn]
    unsigned short* Kb   = (unsigned short*)(W + (8u << 20));    // 8 MB
    unsigned short* Vtb  = (unsigned short*)(W + (16u << 20));   // 8 MB
    unsigned short* Oball= (unsigned short*)(W + (24u << 20));   // 8 MB   [dead after out-proj]
    unsigned short* hb   = (unsigned short*)(W);                 // 32 MB  (reuses Q/K/Vt/O)
    float*          y12  = (float*)(W + (32u << 20));            // 16 MB
    float*          x1   = (float*)(W + (48u << 20));            // 16 MB
    unsigned short* xb   = (unsigned short*)(W + (66u << 20));   // 8 MB
    unsigned short* x1b  = xb;                                   // reuse after QKV GEMM
    unsigned short* Wqkv = (unsigned short*)(W + (74u << 20));   // 1.5 MB
    unsigned short* Wot  = (unsigned short*)(W + (76u << 20));   // 0.5 MB
    unsigned short* W1t  = (unsigned short*)(W + (77u << 20));   // 2 MB
    unsigned short* W2t  = (unsigned short*)(W + (79u << 20));   // 2 MB
    float*          bqkv = (float*)(W + (81u << 20));            // 6 KB
    float*          outp = (float*)d_out;

    // prepass (2 launches)
    conv_bf16<<<dim3(4096), dim3(256), 0, stream>>>(x, xb, NBL * DMODEL);
    prep_weights<<<dim3(769), dim3(256), 0, stream>>>(
        Wq, Wk, Wv, Wo, W1, W2, bq, bk, bv, Wqkv, Wot, W1t, W2t, bqkv);

    // QKV fused projection, scatter to Q/K [bh,l,dk] and V^T [bh,dk,l]
    mfma_gemm<128><<<dim3(12, 64), dim3(256), 0, stream>>>(
        xb, Wqkv, bqkv, nullptr, nullptr, NBL, 1536, 512, 0, 2, Qb, Kb, Vtb);

    // attention (512 blocks x 128 q-rows)
    attn_mfma<<<dim3(512), dim3(256), 0, stream>>>(Qb, Kb, Vtb, bias, mask, Oball);

    // out projection + residual(x) -> y1 (fp32); BN=64 -> 512 blocks
    mfma_gemm<64><<<dim3(8, 64), dim3(256), 0, stream>>>(
        Oball, Wot, bo, x, y12, NBL, 512, 512, 0, 0, nullptr, nullptr, nullptr);

    // LN1 -> x1 (fp32) + x1b (bf16)
    ln_kernel<<<dim3(NBL / 4), dim3(256), 0, stream>>>(y12, ln1g, ln1b, x1, x1b);

    // FFN1: relu(x1 @ W1 + b1) -> hb (bf16)
    mfma_gemm<128><<<dim3(16, 64), dim3(256), 0, stream>>>(
        x1b, W1t, b1, nullptr, hb, NBL, 2048, 512, 1, 1, nullptr, nullptr, nullptr);

    // FFN2: hb @ W2 + b2 + x1 -> y2 (fp32); BN=64 -> 512 blocks
    mfma_gemm<64><<<dim3(8, 64), dim3(256), 0, stream>>>(
        hb, W2t, b2, x1, y12, NBL, 512, 2048, 0, 0, nullptr, nullptr, nullptr);

    // LN2 -> output
    ln_kernel<<<dim3(NBL / 4), dim3(256), 0, stream>>>(y12, ln2g, ln2b, outp, nullptr);
}

// Round 10
// 341.038 us; speedup vs baseline: 1.1232x; 1.1232x over previous
//
#include <hip/hip_runtime.h>
#include <math.h>

#define NHEAD 8
#define DKD 64
#define DMODEL 512
#define LSEQ 1024
#define NBL 8192          // B*L

typedef __attribute__((ext_vector_type(8))) short bf8;   // 8 x bf16 (4 VGPRs)
typedef __attribute__((ext_vector_type(4))) float f4;    // MFMA accumulator

__device__ inline unsigned short f2bf(float f) {
    union { float f; unsigned u; } v; v.f = f;
    unsigned r = v.u + 0x7FFFu + ((v.u >> 16) & 1u);   // RNE
    return (unsigned short)(r >> 16);
}

// v_cvt_pk_bf16_f32: pack two fp32 -> two bf16 in one u32 (T12 recipe)
__device__ __forceinline__ unsigned cvtpk(float lo, float hi) {
    unsigned r;
    asm("v_cvt_pk_bf16_f32 %0, %1, %2" : "=v"(r) : "v"(lo), "v"(hi));
    return r;
}

// async global->LDS, 16B per lane. LDS dest = wave-uniform base + lane*16.
__device__ __forceinline__ void gload16(const void* g, void* l) {
    __builtin_amdgcn_global_load_lds(
        (const __attribute__((address_space(1))) unsigned int*)g,
        (__attribute__((address_space(3))) unsigned int*)l, 16, 0, 0);
}

// ---------------------------------------------------------------------------
// prepass: fp32 -> bf16 elementwise (x)
// ---------------------------------------------------------------------------
__global__ __launch_bounds__(256) void conv_bf16(
    const float* __restrict__ in, unsigned short* __restrict__ out, int n)
{
    int i = (blockIdx.x * 256 + threadIdx.x) * 4;
    if (i >= n) return;
    float4 v = *(const float4*)(in + i);
    ushort4 o;
    o.x = f2bf(v.x); o.y = f2bf(v.y); o.z = f2bf(v.z); o.w = f2bf(v.w);
    *(ushort4*)(out + i) = o;
}

// ---------------------------------------------------------------------------
// prepass: biasMb[b][q][k] = bf16( bias + (mask[b][k] ? -1e30 : 0) )
// ---------------------------------------------------------------------------
__global__ __launch_bounds__(256) void biasmb_kernel(
    const float* __restrict__ bias, const unsigned char* __restrict__ mask,
    unsigned short* __restrict__ o)
{
    size_t flat = ((size_t)blockIdx.x * 256 + threadIdx.x) * 8;
    int b = (int)(flat >> 20);
    int k = (int)(flat & 1023);
    float4 v0 = *(const float4*)(bias + flat);
    float4 v1 = *(const float4*)(bias + flat + 4);
    uint2 mk = *(const uint2*)(mask + b * 1024 + k);
    float vs[8] = {v0.x, v0.y, v0.z, v0.w, v1.x, v1.y, v1.z, v1.w};
    unsigned mw[2] = {mk.x, mk.y};
    unsigned short os[8];
    #pragma unroll
    for (int j = 0; j < 8; ++j) {
        unsigned mb = (mw[j >> 2] >> ((j & 3) * 8)) & 0xffu;
        os[j] = f2bf(mb ? -1e30f : vs[j]);
    }
    uint4 pk;
    pk.x = (unsigned)os[0] | ((unsigned)os[1] << 16);
    pk.y = (unsigned)os[2] | ((unsigned)os[3] << 16);
    pk.z = (unsigned)os[4] | ((unsigned)os[5] << 16);
    pk.w = (unsigned)os[6] | ((unsigned)os[7] << 16);
    *(uint4*)(o + flat) = pk;
}

// ---------------------------------------------------------------------------
// prepass: all weight transposes + bias concat in ONE launch (769 blocks)
// ---------------------------------------------------------------------------
__device__ __forceinline__ void do_transpose(
    const float* __restrict__ W, unsigned short* __restrict__ Wt,
    int K, int N, int bx, int by)
{
    __shared__ float tile[64][65];
    const int k0 = by * 64, n0 = bx * 64;
    const int c = threadIdx.x & 63, r0 = (threadIdx.x >> 6) * 16;
    #pragma unroll
    for (int i = 0; i < 16; ++i)
        tile[r0 + i][c] = W[(size_t)(k0 + r0 + i) * N + n0 + c];
    __syncthreads();
    #pragma unroll
    for (int i = 0; i < 16; ++i)
        Wt[(size_t)(n0 + r0 + i) * K + k0 + c] = f2bf(tile[c][r0 + i]);
}

__global__ __launch_bounds__(256) void prep_weights(
    const float* __restrict__ Wq, const float* __restrict__ Wk,
    const float* __restrict__ Wv, const float* __restrict__ Wo,
    const float* __restrict__ W1, const float* __restrict__ W2,
    const float* __restrict__ bq, const float* __restrict__ bk,
    const float* __restrict__ bv,
    unsigned short* __restrict__ Wqkv, unsigned short* __restrict__ Wot,
    unsigned short* __restrict__ W1t, unsigned short* __restrict__ W2t,
    float* __restrict__ bqkv)
{
    int j = blockIdx.x;
    if (j < 256) {                               // four 512x512 transposes
        int which = j >> 6, tt = j & 63;
        const float* src = which == 0 ? Wq : which == 1 ? Wk : which == 2 ? Wv : Wo;
        unsigned short* dst = which == 0 ? Wqkv : which == 1 ? (Wqkv + 262144)
                            : which == 2 ? (Wqkv + 524288) : Wot;
        do_transpose(src, dst, 512, 512, tt & 7, tt >> 3);
    } else if (j < 512) {                        // W1: [512,2048]
        int tt = j - 256;
        do_transpose(W1, W1t, 512, 2048, tt & 31, tt >> 5);
    } else if (j < 768) {                        // W2: [2048,512]
        int tt = j - 512;
        do_transpose(W2, W2t, 2048, 512, tt & 7, tt >> 3);
    } else {                                     // concat qkv biases
        for (int c = threadIdx.x; c < 1536; c += 256)
            bqkv[c] = c < 512 ? bq[c] : c < 1024 ? bk[c - 512] : bv[c - 1024];
    }
}

// ---------------------------------------------------------------------------
// bf16 MFMA GEMM: C[M,N] = A[M,K] @ Bt[N,K]^T + bias. Tile 128 x BN, 4 waves.
// BK=64; DOUBLE-BUFFERED LDS: stage(next) -> compute(cur) -> 1 barrier/step.
// global_load_lds (16B) with pre-swizzled source chunk; linear LDS;
// XOR-swizzled reads -> conflict-free ds_read_b128.
// outmode: 0 = fp32 [M,N] (+resid), 1 = bf16 [M,N] (+relu), 2 = QKV scatter
// ---------------------------------------------------------------------------
template<int BN>
__global__ __launch_bounds__(256) void mfma_gemm(
    const unsigned short* __restrict__ A, const unsigned short* __restrict__ Bt,
    const float* __restrict__ bias, const float* __restrict__ resid,
    void* __restrict__ outp, int M, int N, int K, int relu, int outmode,
    unsigned short* __restrict__ qs, unsigned short* __restrict__ ks,
    unsigned short* __restrict__ vts)
{
    __shared__ uint4 As[2][1024];       // [buf][128 rows x 8 chunks]
    __shared__ uint4 Bs[2][BN * 8];
    constexpr int NB = BN / 32;         // acc cols per wave

    const int t = threadIdx.x;
    const int lane = t & 63, w = t >> 6;
    const int g = lane >> 4, r15 = lane & 15;
    const int wr = w >> 1, wc = w & 1;
    const int rowBase = blockIdx.y * 128, colBase = blockIdx.x * BN;

    f4 acc[4][NB] = {};

    const int r   = t >> 3;                    // w*8 + (lane>>3)
    const int chs = (t & 7) ^ (r & 7);         // pre-swizzled source chunk
    const unsigned short* Ag0 = A  + (size_t)(rowBase + r) * K + chs * 8;
    const unsigned short* Bg0 = Bt + (size_t)(colBase + r) * K + chs * 8;

    auto stage = [&](int buf, int k0) {
        unsigned short* Al = (unsigned short*)As[buf] + (w * 8) * 64;
        unsigned short* Bl = (unsigned short*)Bs[buf] + (w * 8) * 64;
        const unsigned short* Ag = Ag0 + k0;
        const unsigned short* Bg = Bg0 + k0;
        #pragma unroll
        for (int p = 0; p < 4; ++p)
            gload16(Ag + (size_t)(p * 32) * K, Al + p * 32 * 64);
        #pragma unroll
        for (int p = 0; p < NB; ++p)
            gload16(Bg + (size_t)(p * 32) * K, Bl + p * 32 * 64);
    };

    const int nst = K >> 6;
    stage(0, 0);
    __syncthreads();

    for (int it = 0; it < nst; ++it) {
        const int cur = it & 1;
        if (it + 1 < nst) stage(cur ^ 1, (it + 1) << 6);
        #pragma unroll
        for (int kk = 0; kk < 2; ++kk) {
            bf8 af[4], bfr[NB];
            #pragma unroll
            for (int m = 0; m < 4; ++m) {
                int ra = wr * 64 + m * 16 + r15;
                af[m] = *(const bf8*)&As[cur][ra * 8 + ((kk * 4 + g) ^ (ra & 7))];
            }
            #pragma unroll
            for (int n = 0; n < NB; ++n) {
                int rb = wc * (BN / 2) + n * 16 + r15;
                bfr[n] = *(const bf8*)&Bs[cur][rb * 8 + ((kk * 4 + g) ^ (rb & 7))];
            }
            #pragma unroll
            for (int m = 0; m < 4; ++m)
                #pragma unroll
                for (int n = 0; n < NB; ++n)
                    acc[m][n] = __builtin_amdgcn_mfma_f32_16x16x32_bf16(
                        af[m], bfr[n], acc[m][n], 0, 0, 0);
        }
        __syncthreads();
    }

    #pragma unroll
    for (int m = 0; m < 4; ++m) {
        #pragma unroll
        for (int n = 0; n < NB; ++n) {
            int col = colBase + wc * (BN / 2) + n * 16 + r15;
            float bv = bias[col];
            #pragma unroll
            for (int rr = 0; rr < 4; ++rr) {
                int row = rowBase + wr * 64 + m * 16 + g * 4 + rr;
                float v = acc[m][n][rr] + bv;
                if (relu) v = fmaxf(v, 0.f);
                if (outmode == 0) {
                    size_t idx = (size_t)row * N + col;
                    if (resid) v += resid[idx];
                    ((float*)outp)[idx] = v;
                } else if (outmode == 1) {
                    ((unsigned short*)outp)[(size_t)row * N + col] = f2bf(v);
                } else {
                    int sel = col >> 9, hd = col & 511;
                    int h = hd >> 6, dk = hd & 63;
                    int b = row >> 10, l = row & 1023;
                    unsigned short bw = f2bf(v);
                    size_t bh = (size_t)(b * NHEAD + h);
                    if (sel == 0)      qs[(bh * LSEQ + l) * DKD + dk] = bw;
                    else if (sel == 1) ks[(bh * LSEQ + l) * DKD + dk] = bw;
                    else               vts[(bh * DKD + dk) * LSEQ + l] = bw;
                }
            }
        }
    }
}

// ---------------------------------------------------------------------------
// Flash attention v5. Block = 128 q-rows of one (b,h), 4 waves x 32 rows.
// Swapped QK^T (lane owns one q-row). K/V AND bf16 bias tiles double-buffered
// via global_load_lds (pre-swizzled source; XOR-swizzled LDS reads).
// Softmax reads bias from LDS (latency hidden by async staging). Low VGPR.
// setprio(1) around MFMA clusters (T5); defer-max (T13); cvt_pk P pack (T12).
// ---------------------------------------------------------------------------
__global__ __launch_bounds__(256) void attn_mfma(
    const unsigned short* __restrict__ Qg, const unsigned short* __restrict__ Kg,
    const unsigned short* __restrict__ Vtg, const unsigned short* __restrict__ biasMb,
    unsigned short* __restrict__ Ob)
{
    __shared__ uint4 Ks[2][512];         // [buf][64 keys x 8 chunks]   16 KB
    __shared__ uint4 Vs[2][512];         // [buf][64 dk x 8 key-chunks] 16 KB
    __shared__ uint4 Bls[2][1024];       // [buf][128 q-rows x 64 keys bf16] 32 KB
    __shared__ unsigned int Pb[4096];    // 4 waves x 32 rows x 64 keys bf16 16 KB

    const int t = threadIdx.x;
    const int lane = t & 63, w = t >> 6;
    const int g = lane >> 4, r15 = lane & 15;

    // XCD-aware remap (512 blocks, 64 per XCD chunk)
    const int p = blockIdx.x;
    const int logical = (p & 7) * 64 + (p >> 3);
    const int bh = logical >> 3, qt = logical & 7;
    const int b = bh >> 3, h = bh & 7;
    const int qbase = qt * 128 + w * 32;

    bf8 qf[2][2];
    #pragma unroll
    for (int u = 0; u < 2; ++u) {
        const unsigned short* qp = Qg + ((size_t)bh * LSEQ + qbase + u * 16 + r15) * DKD + g * 8;
        qf[u][0] = *(const bf8*)qp;
        qf[u][1] = *(const bf8*)(qp + 32);
    }

    float mrun[2] = {-1e30f, -1e30f}, lsum[2] = {0.f, 0.f};
    f4 oacc[2][4] = {};

    const int sr   = t >> 3;                   // 0..31 (K/V staging row)
    const int chs  = (t & 7) ^ (sr & 7);       // pre-swizzled source chunk
    const int brow = lane >> 3;                // 0..7  (bias staging row-in-group)
    const int bch  = (lane & 7) ^ brow;        // pre-swizzled bias source chunk
    unsigned short* Pw = (unsigned short*)(Pb + w * 1024);

    const size_t kBase = (size_t)bh * LSEQ * DKD;   // K rows
    const size_t vBase = (size_t)bh * DKD * LSEQ;   // V^T rows
    const unsigned short* bB = biasMb + ((size_t)b << 20);

    auto stage = [&](int buf, int key0) {
        const unsigned short* Kgp = Kg  + kBase + (size_t)(key0 + sr) * DKD + chs * 8;
        const unsigned short* Vgp = Vtg + vBase + (size_t)sr * LSEQ + key0 + chs * 8;
        unsigned short* Kl = (unsigned short*)Ks[buf] + (w * 8) * 64;
        unsigned short* Vl = (unsigned short*)Vs[buf] + (w * 8) * 64;
        gload16(Kgp, Kl);
        gload16(Kgp + (size_t)32 * DKD, Kl + 32 * 64);
        gload16(Vgp, Vl);
        gload16(Vgp + (size_t)32 * LSEQ, Vl + 32 * 64);
        unsigned short* Bl = (unsigned short*)Bls[buf] + w * 2048;   // 4KB/wave
        #pragma unroll
        for (int pp = 0; pp < 4; ++pp) {
            const unsigned short* Bgp = bB + (size_t)(qbase + pp * 8 + brow) * 1024
                                      + key0 + bch * 8;
            gload16(Bgp, Bl + pp * 512);
        }
    };

    stage(0, 0);
    __syncthreads();

    for (int kt = 0; kt < 16; ++kt) {
        const int cur = kt & 1;
        if (kt < 15) stage(cur ^ 1, (kt + 1) * 64);

        const char* Bw = (const char*)Bls[cur] + w * 4096;

        // S^T = K Q for both q-groups (K frags shared)
        f4 sacc[2][4] = {};
        __builtin_amdgcn_s_setprio(1);
        #pragma unroll
        for (int kk = 0; kk < 2; ++kk)
            #pragma unroll
            for (int m = 0; m < 4; ++m) {
                int row = m * 16 + r15;
                bf8 kf = *(const bf8*)&Ks[cur][row * 8 + ((kk * 4 + g) ^ (row & 7))];
                sacc[0][m] = __builtin_amdgcn_mfma_f32_16x16x32_bf16(kf, qf[0][kk], sacc[0][m], 0, 0, 0);
                sacc[1][m] = __builtin_amdgcn_mfma_f32_16x16x32_bf16(kf, qf[1][kk], sacc[1][m], 0, 0, 0);
            }
        __builtin_amdgcn_s_setprio(0);

        // softmax per q-group (per-lane over 16 keys + 2 shfl); bias from LDS
        #pragma unroll
        for (int u = 0; u < 2; ++u) {
            float s[16];
            float pmax = -1e30f;
            #pragma unroll
            for (int m = 0; m < 4; ++m) {
                int off = (u * 16 + r15) * 128 + ((m * 32 + g * 8) ^ ((r15 & 7) << 4));
                uint2 bv = *(const uint2*)(Bw + off);
                float b0 = __uint_as_float(bv.x << 16);
                float b1 = __uint_as_float(bv.x & 0xffff0000u);
                float b2 = __uint_as_float(bv.y << 16);
                float b3 = __uint_as_float(bv.y & 0xffff0000u);
                s[m * 4 + 0] = fmaf(sacc[u][m][0], 0.125f, b0);
                s[m * 4 + 1] = fmaf(sacc[u][m][1], 0.125f, b1);
                s[m * 4 + 2] = fmaf(sacc[u][m][2], 0.125f, b2);
                s[m * 4 + 3] = fmaf(sacc[u][m][3], 0.125f, b3);
                #pragma unroll
                for (int j = 0; j < 4; ++j) pmax = fmaxf(pmax, s[m * 4 + j]);
            }
            pmax = fmaxf(pmax, __shfl_xor(pmax, 16));
            pmax = fmaxf(pmax, __shfl_xor(pmax, 32));

            if (!__all(pmax <= mrun[u] + 8.f)) {     // defer-max (T13)
                float mnew = fmaxf(mrun[u], pmax);
                float scale = __expf(mrun[u] - mnew);
                lsum[u] *= scale;
                #pragma unroll
                for (int m = 0; m < 4; ++m)
                    #pragma unroll
                    for (int j = 0; j < 4; ++j) oacc[u][m][j] *= scale;
                mrun[u] = mnew;
            }

            float psum = 0.f;
            #pragma unroll
            for (int i = 0; i < 16; ++i) { s[i] = __expf(s[i] - mrun[u]); psum += s[i]; }
            psum += __shfl_xor(psum, 16);
            psum += __shfl_xor(psum, 32);
            lsum[u] += psum;

            // pack P -> per-wave LDS (bf16, XOR-swizzled), wave-private
            #pragma unroll
            for (int m = 0; m < 4; ++m) {
                uint2 pk;
                pk.x = cvtpk(s[m * 4 + 0], s[m * 4 + 1]);
                pk.y = cvtpk(s[m * 4 + 2], s[m * 4 + 3]);
                int off = ((u * 16 + r15) * 128 + m * 32 + g * 8) ^ ((r15 & 7) << 4);
                *(uint2*)((char*)Pw + off) = pk;
            }
        }

        // O^T += V^T P (V frags shared across q-groups)
        #pragma unroll
        for (int kk = 0; kk < 2; ++kk) {
            bf8 pf[2];
            #pragma unroll
            for (int u = 0; u < 2; ++u) {
                int off = ((u * 16 + r15) * 128 + kk * 64 + g * 16) ^ ((r15 & 7) << 4);
                pf[u] = *(const bf8*)((char*)Pw + off);
            }
            __builtin_amdgcn_s_setprio(1);
            #pragma unroll
            for (int m = 0; m < 4; ++m) {
                int row = m * 16 + r15;
                bf8 vf = *(const bf8*)&Vs[cur][row * 8 + ((kk * 4 + g) ^ (row & 7))];
                oacc[0][m] = __builtin_amdgcn_mfma_f32_16x16x32_bf16(vf, pf[0], oacc[0][m], 0, 0, 0);
                oacc[1][m] = __builtin_amdgcn_mfma_f32_16x16x32_bf16(vf, pf[1], oacc[1][m], 0, 0, 0);
            }
            __builtin_amdgcn_s_setprio(0);
        }
        __syncthreads();   // staged tile ready; all waves done with cur buffers
    }

    #pragma unroll
    for (int u = 0; u < 2; ++u) {
        float inv = 1.f / lsum[u];
        unsigned short* op = Ob + ((size_t)b * LSEQ + qbase + u * 16 + r15) * DMODEL + h * DKD;
        #pragma unroll
        for (int m = 0; m < 4; ++m) {
            ushort4 o4;
            o4.x = f2bf(oacc[u][m][0] * inv);
            o4.y = f2bf(oacc[u][m][1] * inv);
            o4.z = f2bf(oacc[u][m][2] * inv);
            o4.w = f2bf(oacc[u][m][3] * inv);
            *(ushort4*)(op + m * 16 + g * 4) = o4;
        }
    }
}

// ---------------------------------------------------------------------------
// LayerNorm (fp32), optional bf16 secondary output. One wave per row of 512.
// ---------------------------------------------------------------------------
__global__ __launch_bounds__(256) void ln_kernel(
    const float* __restrict__ in, const float* __restrict__ g,
    const float* __restrict__ bt, float* __restrict__ out,
    unsigned short* __restrict__ outb)
{
    const int row  = blockIdx.x * 4 + (threadIdx.x >> 6);
    const int lane = threadIdx.x & 63;
    const float* rp = in + (size_t)row * DMODEL + lane * 8;
    float4 x0 = *(const float4*)rp;
    float4 x1 = *(const float4*)(rp + 4);
    float xs[8] = {x0.x, x0.y, x0.z, x0.w, x1.x, x1.y, x1.z, x1.w};

    float sum = 0.f;
    #pragma unroll
    for (int i = 0; i < 8; ++i) sum += xs[i];
    #pragma unroll
    for (int off = 32; off; off >>= 1) sum += __shfl_xor(sum, off);
    float mu = sum * (1.f / 512.f);

    float vs = 0.f;
    #pragma unroll
    for (int i = 0; i < 8; ++i) { float d = xs[i] - mu; vs += d * d; }
    #pragma unroll
    for (int off = 32; off; off >>= 1) vs += __shfl_xor(vs, off);
    float rs = rsqrtf(vs * (1.f / 512.f) + 1e-5f);

    const float* gp = g  + lane * 8;
    const float* bp = bt + lane * 8;
    float4 g0 = *(const float4*)gp, g1 = *(const float4*)(gp + 4);
    float4 b0 = *(const float4*)bp, b1 = *(const float4*)(bp + 4);
    float gs[8] = {g0.x, g0.y, g0.z, g0.w, g1.x, g1.y, g1.z, g1.w};
    float bs[8] = {b0.x, b0.y, b0.z, b0.w, b1.x, b1.y, b1.z, b1.w};

    float res[8];
    #pragma unroll
    for (int i = 0; i < 8; ++i) res[i] = (xs[i] - mu) * rs * gs[i] + bs[i];

    float* op = out + (size_t)row * DMODEL + lane * 8;
    float4 r0 = {res[0], res[1], res[2], res[3]};
    float4 r1 = {res[4], res[5], res[6], res[7]};
    *(float4*)op       = r0;
    *(float4*)(op + 4) = r1;

    if (outb) {
        unsigned short* ob = outb + (size_t)row * DMODEL + lane * 8;
        ushort4 u0, u1;
        u0.x = f2bf(res[0]); u0.y = f2bf(res[1]); u0.z = f2bf(res[2]); u0.w = f2bf(res[3]);
        u1.x = f2bf(res[4]); u1.y = f2bf(res[5]); u1.z = f2bf(res[6]); u1.w = f2bf(res[7]);
        *(ushort4*)ob       = u0;
        *(ushort4*)(ob + 4) = u1;
    }
}

// ---------------------------------------------------------------------------
extern "C" void kernel_launch(void* const* d_in, const int* in_sizes, int n_in,
                              void* d_out, int out_size, void* d_ws, size_t ws_size,
                              hipStream_t stream)
{
    const float*         x    = (const float*)d_in[0];
    const unsigned char* mask = (const unsigned char*)d_in[1];
    const float*         bias = (const float*)d_in[2];
    const float* Wq = (const float*)d_in[3];
    const float* bq = (const float*)d_in[4];
    const float* Wk = (const float*)d_in[5];
    const float* bk = (const float*)d_in[6];
    const float* Wv = (const float*)d_in[7];
    const float* bv = (const float*)d_in[8];
    const float* Wo = (const float*)d_in[9];
    const float* bo = (const float*)d_in[10];
    const float* ln1g = (const float*)d_in[11];
    const float* ln1b = (const float*)d_in[12];
    const float* W1 = (const float*)d_in[13];
    const float* b1 = (const float*)d_in[14];
    const float* W2 = (const float*)d_in[15];
    const float* b2 = (const float*)d_in[16];
    const float* ln2g = (const float*)d_in[17];
    const float* ln2b = (const float*)d_in[18];

    char* W = (char*)d_ws;
    unsigned short* Qb   = (unsigned short*)(W);                 // 8 MB   [dead after attn]
    unsigned short* Kb   = (unsigned short*)(W + (8u << 20));    // 8 MB
    unsigned short* Vtb  = (unsigned short*)(W + (16u << 20));   // 8 MB
    unsigned short* Oball= (unsigned short*)(W + (24u << 20));   // 8 MB   [dead after out-proj]
    unsigned short* hb   = (unsigned short*)(W);                 // 32 MB  (reuses Q/K/Vt/O)
    unsigned short* biasMb=(unsigned short*)(W + (32u << 20));   // 16.8 MB [dead after attn]
    float*          y12  = (float*)(W + (32u << 20));            // 16 MB  (reuses biasMb lo)
    float*          x1   = (float*)(W + (49u << 20));            // 16 MB
    unsigned short* xb   = (unsigned short*)(W + (66u << 20));   // 8 MB
    unsigned short* x1b  = xb;                                   // reuse after QKV GEMM
    unsigned short* Wqkv = (unsigned short*)(W + (74u << 20));   // 1.5 MB
    unsigned short* Wot  = (unsigned short*)(W + (76u << 20));   // 0.5 MB
    unsigned short* W1t  = (unsigned short*)(W + (77u << 20));   // 2 MB
    unsigned short* W2t  = (unsigned short*)(W + (79u << 20));   // 2 MB
    float*          bqkv = (float*)(W + (81u << 20));            // 6 KB
    float*          outp = (float*)d_out;

    // prepass (3 launches)
    conv_bf16<<<dim3(4096), dim3(256), 0, stream>>>(x, xb, NBL * DMODEL);
    prep_weights<<<dim3(769), dim3(256), 0, stream>>>(
        Wq, Wk, Wv, Wo, W1, W2, bq, bk, bv, Wqkv, Wot, W1t, W2t, bqkv);
    biasmb_kernel<<<dim3(4096), dim3(256), 0, stream>>>(bias, mask, biasMb);

    // QKV fused projection, scatter to Q/K [bh,l,dk] and V^T [bh,dk,l]
    mfma_gemm<128><<<dim3(12, 64), dim3(256), 0, stream>>>(
        xb, Wqkv, bqkv, nullptr, nullptr, NBL, 1536, 512, 0, 2, Qb, Kb, Vtb);

    // attention (512 blocks x 128 q-rows)
    attn_mfma<<<dim3(512), dim3(256), 0, stream>>>(Qb, Kb, Vtb, biasMb, Oball);

    // out projection + residual(x) -> y1 (fp32); BN=64 -> 512 blocks
    mfma_gemm<64><<<dim3(8, 64), dim3(256), 0, stream>>>(
        Oball, Wot, bo, x, y12, NBL, 512, 512, 0, 0, nullptr, nullptr, nullptr);

    // LN1 -> x1 (fp32) + x1b (bf16)
    ln_kernel<<<dim3(NBL / 4), dim3(256), 0, stream>>>(y12, ln1g, ln1b, x1, x1b);

    // FFN1: relu(x1 @ W1 + b1) -> hb (bf16)
    mfma_gemm<128><<<dim3(16, 64), dim3(256), 0, stream>>>(
        x1b, W1t, b1, nullptr, hb, NBL, 2048, 512, 1, 1, nullptr, nullptr, nullptr);

    // FFN2: hb @ W2 + b2 + x1 -> y2 (fp32); BN=64 -> 512 blocks
    mfma_gemm<64><<<dim3(8, 64), dim3(256), 0, stream>>>(
        hb, W2t, b2, x1, y12, NBL, 512, 2048, 0, 0, nullptr, nullptr, nullptr);

    // LN2 -> output
    ln_kernel<<<dim3(NBL / 4), dim3(256), 0, stream>>>(y12, ln2g, ln2b, outp, nullptr);
}

// Round 11
// 327.945 us; speedup vs baseline: 1.1681x; 1.0399x over previous
//
#include <hip/hip_runtime.h>
#include <math.h>

#define NHEAD 8
#define DKD 64
#define DMODEL 512
#define LSEQ 1024
#define NBL 8192          // B*L

typedef __attribute__((ext_vector_type(8))) short bf8;   // 8 x bf16 (4 VGPRs)
typedef __attribute__((ext_vector_type(4))) float f4;    // MFMA accumulator

__device__ inline unsigned short f2bf(float f) {
    union { float f; unsigned u; } v; v.f = f;
    unsigned r = v.u + 0x7FFFu + ((v.u >> 16) & 1u);   // RNE
    return (unsigned short)(r >> 16);
}

// v_cvt_pk_bf16_f32: pack two fp32 -> two bf16 in one u32 (T12 recipe)
__device__ __forceinline__ unsigned cvtpk(float lo, float hi) {
    unsigned r;
    asm("v_cvt_pk_bf16_f32 %0, %1, %2" : "=v"(r) : "v"(lo), "v"(hi));
    return r;
}

// async global->LDS, 16B per lane. LDS dest = wave-uniform base + lane*16.
__device__ __forceinline__ void gload16(const void* g, void* l) {
    __builtin_amdgcn_global_load_lds(
        (const __attribute__((address_space(1))) unsigned int*)g,
        (__attribute__((address_space(3))) unsigned int*)l, 16, 0, 0);
}

// ---------------------------------------------------------------------------
// prepass: fp32 -> bf16 elementwise (x)
// ---------------------------------------------------------------------------
__global__ __launch_bounds__(256) void conv_bf16(
    const float* __restrict__ in, unsigned short* __restrict__ out, int n)
{
    int i = (blockIdx.x * 256 + threadIdx.x) * 4;
    if (i >= n) return;
    float4 v = *(const float4*)(in + i);
    ushort4 o;
    o.x = f2bf(v.x); o.y = f2bf(v.y); o.z = f2bf(v.z); o.w = f2bf(v.w);
    *(ushort4*)(out + i) = o;
}

// ---------------------------------------------------------------------------
// prepass: biasMb[b][q][k] = bf16( bias + (mask[b][k] ? -1e30 : 0) )
// ---------------------------------------------------------------------------
__global__ __launch_bounds__(256) void biasmb_kernel(
    const float* __restrict__ bias, const unsigned char* __restrict__ mask,
    unsigned short* __restrict__ o)
{
    size_t flat = ((size_t)blockIdx.x * 256 + threadIdx.x) * 8;
    int b = (int)(flat >> 20);
    int k = (int)(flat & 1023);
    float4 v0 = *(const float4*)(bias + flat);
    float4 v1 = *(const float4*)(bias + flat + 4);
    uint2 mk = *(const uint2*)(mask + b * 1024 + k);
    float vs[8] = {v0.x, v0.y, v0.z, v0.w, v1.x, v1.y, v1.z, v1.w};
    unsigned mw[2] = {mk.x, mk.y};
    unsigned short os[8];
    #pragma unroll
    for (int j = 0; j < 8; ++j) {
        unsigned mb = (mw[j >> 2] >> ((j & 3) * 8)) & 0xffu;
        os[j] = f2bf(mb ? -1e30f : vs[j]);
    }
    uint4 pk;
    pk.x = (unsigned)os[0] | ((unsigned)os[1] << 16);
    pk.y = (unsigned)os[2] | ((unsigned)os[3] << 16);
    pk.z = (unsigned)os[4] | ((unsigned)os[5] << 16);
    pk.w = (unsigned)os[6] | ((unsigned)os[7] << 16);
    *(uint4*)(o + flat) = pk;
}

// ---------------------------------------------------------------------------
// prepass: all weight transposes + bias concat in ONE launch (769 blocks)
// ---------------------------------------------------------------------------
__device__ __forceinline__ void do_transpose(
    const float* __restrict__ W, unsigned short* __restrict__ Wt,
    int K, int N, int bx, int by)
{
    __shared__ float tile[64][65];
    const int k0 = by * 64, n0 = bx * 64;
    const int c = threadIdx.x & 63, r0 = (threadIdx.x >> 6) * 16;
    #pragma unroll
    for (int i = 0; i < 16; ++i)
        tile[r0 + i][c] = W[(size_t)(k0 + r0 + i) * N + n0 + c];
    __syncthreads();
    #pragma unroll
    for (int i = 0; i < 16; ++i)
        Wt[(size_t)(n0 + r0 + i) * K + k0 + c] = f2bf(tile[c][r0 + i]);
}

__global__ __launch_bounds__(256) void prep_weights(
    const float* __restrict__ Wq, const float* __restrict__ Wk,
    const float* __restrict__ Wv, const float* __restrict__ Wo,
    const float* __restrict__ W1, const float* __restrict__ W2,
    const float* __restrict__ bq, const float* __restrict__ bk,
    const float* __restrict__ bv,
    unsigned short* __restrict__ Wqkv, unsigned short* __restrict__ Wot,
    unsigned short* __restrict__ W1t, unsigned short* __restrict__ W2t,
    float* __restrict__ bqkv)
{
    int j = blockIdx.x;
    if (j < 256) {                               // four 512x512 transposes
        int which = j >> 6, tt = j & 63;
        const float* src = which == 0 ? Wq : which == 1 ? Wk : which == 2 ? Wv : Wo;
        unsigned short* dst = which == 0 ? Wqkv : which == 1 ? (Wqkv + 262144)
                            : which == 2 ? (Wqkv + 524288) : Wot;
        do_transpose(src, dst, 512, 512, tt & 7, tt >> 3);
    } else if (j < 512) {                        // W1: [512,2048]
        int tt = j - 256;
        do_transpose(W1, W1t, 512, 2048, tt & 31, tt >> 5);
    } else if (j < 768) {                        // W2: [2048,512]
        int tt = j - 512;
        do_transpose(W2, W2t, 2048, 512, tt & 7, tt >> 3);
    } else {                                     // concat qkv biases
        for (int c = threadIdx.x; c < 1536; c += 256)
            bqkv[c] = c < 512 ? bq[c] : c < 1024 ? bk[c - 512] : bv[c - 1024];
    }
}

// ---------------------------------------------------------------------------
// bf16 MFMA GEMM: C[M,N] = A[M,K] @ Bt[N,K]^T + bias. Tile 128 x BN, 4 waves.
// BK=64; DOUBLE-BUFFERED LDS; global_load_lds staging; XOR-swizzled reads.
// XCD-aware bijective block remap (T1): consecutive blocks sharing an A
// row-panel land on ONE XCD's L2 -> A fetched once per XCD, not 8x.
// outmode: 0 = fp32 [M,N] (+resid), 1 = bf16 [M,N] (+relu), 2 = QKV scatter
// ---------------------------------------------------------------------------
template<int BN>
__global__ __launch_bounds__(256) void mfma_gemm(
    const unsigned short* __restrict__ A, const unsigned short* __restrict__ Bt,
    const float* __restrict__ bias, const float* __restrict__ resid,
    void* __restrict__ outp, int M, int N, int K, int relu, int outmode,
    unsigned short* __restrict__ qs, unsigned short* __restrict__ ks,
    unsigned short* __restrict__ vts)
{
    __shared__ uint4 As[2][1024];       // [buf][128 rows x 8 chunks]
    __shared__ uint4 Bs[2][BN * 8];
    constexpr int NB = BN / 32;         // acc cols per wave

    const int t = threadIdx.x;
    const int lane = t & 63, w = t >> 6;
    const int g = lane >> 4, r15 = lane & 15;
    const int wr = w >> 1, wc = w & 1;

    // T1: bijective XCD swizzle (nwg % 8 == 0 for all launches here)
    const int nwg  = gridDim.x * gridDim.y;
    const int flat = blockIdx.y * gridDim.x + blockIdx.x;
    const int swz  = (flat & 7) * (nwg >> 3) + (flat >> 3);
    const int bx   = swz % gridDim.x, by = swz / gridDim.x;
    const int rowBase = by * 128, colBase = bx * BN;

    f4 acc[4][NB] = {};

    const int r   = t >> 3;                    // w*8 + (lane>>3)
    const int chs = (t & 7) ^ (r & 7);         // pre-swizzled source chunk
    const unsigned short* Ag0 = A  + (size_t)(rowBase + r) * K + chs * 8;
    const unsigned short* Bg0 = Bt + (size_t)(colBase + r) * K + chs * 8;

    auto stage = [&](int buf, int k0) {
        unsigned short* Al = (unsigned short*)As[buf] + (w * 8) * 64;
        unsigned short* Bl = (unsigned short*)Bs[buf] + (w * 8) * 64;
        const unsigned short* Ag = Ag0 + k0;
        const unsigned short* Bg = Bg0 + k0;
        #pragma unroll
        for (int p = 0; p < 4; ++p)
            gload16(Ag + (size_t)(p * 32) * K, Al + p * 32 * 64);
        #pragma unroll
        for (int p = 0; p < NB; ++p)
            gload16(Bg + (size_t)(p * 32) * K, Bl + p * 32 * 64);
    };

    const int nst = K >> 6;
    stage(0, 0);
    __syncthreads();

    for (int it = 0; it < nst; ++it) {
        const int cur = it & 1;
        if (it + 1 < nst) stage(cur ^ 1, (it + 1) << 6);
        #pragma unroll
        for (int kk = 0; kk < 2; ++kk) {
            bf8 af[4], bfr[NB];
            #pragma unroll
            for (int m = 0; m < 4; ++m) {
                int ra = wr * 64 + m * 16 + r15;
                af[m] = *(const bf8*)&As[cur][ra * 8 + ((kk * 4 + g) ^ (ra & 7))];
            }
            #pragma unroll
            for (int n = 0; n < NB; ++n) {
                int rb = wc * (BN / 2) + n * 16 + r15;
                bfr[n] = *(const bf8*)&Bs[cur][rb * 8 + ((kk * 4 + g) ^ (rb & 7))];
            }
            #pragma unroll
            for (int m = 0; m < 4; ++m)
                #pragma unroll
                for (int n = 0; n < NB; ++n)
                    acc[m][n] = __builtin_amdgcn_mfma_f32_16x16x32_bf16(
                        af[m], bfr[n], acc[m][n], 0, 0, 0);
        }
        __syncthreads();
    }

    #pragma unroll
    for (int m = 0; m < 4; ++m) {
        #pragma unroll
        for (int n = 0; n < NB; ++n) {
            int col = colBase + wc * (BN / 2) + n * 16 + r15;
            float bv = bias[col];
            #pragma unroll
            for (int rr = 0; rr < 4; ++rr) {
                int row = rowBase + wr * 64 + m * 16 + g * 4 + rr;
                float v = acc[m][n][rr] + bv;
                if (relu) v = fmaxf(v, 0.f);
                if (outmode == 0) {
                    size_t idx = (size_t)row * N + col;
                    if (resid) v += resid[idx];
                    ((float*)outp)[idx] = v;
                } else if (outmode == 1) {
                    ((unsigned short*)outp)[(size_t)row * N + col] = f2bf(v);
                } else {
                    int sel = col >> 9, hd = col & 511;
                    int h = hd >> 6, dk = hd & 63;
                    int b = row >> 10, l = row & 1023;
                    unsigned short bw = f2bf(v);
                    size_t bh = (size_t)(b * NHEAD + h);
                    if (sel == 0)      qs[(bh * LSEQ + l) * DKD + dk] = bw;
                    else if (sel == 1) ks[(bh * LSEQ + l) * DKD + dk] = bw;
                    else               vts[(bh * DKD + dk) * LSEQ + l] = bw;
                }
            }
        }
    }
}

// ---------------------------------------------------------------------------
// Flash attention v5. Block = 128 q-rows of one (b,h), 4 waves x 32 rows.
// Swapped QK^T (lane owns one q-row). K/V AND bf16 bias tiles double-buffered
// via global_load_lds (pre-swizzled source; XOR-swizzled LDS reads).
// Softmax reads bias from LDS (latency hidden by async staging). Low VGPR.
// setprio(1) around MFMA clusters (T5); defer-max (T13); cvt_pk P pack (T12).
// ---------------------------------------------------------------------------
__global__ __launch_bounds__(256) void attn_mfma(
    const unsigned short* __restrict__ Qg, const unsigned short* __restrict__ Kg,
    const unsigned short* __restrict__ Vtg, const unsigned short* __restrict__ biasMb,
    unsigned short* __restrict__ Ob)
{
    __shared__ uint4 Ks[2][512];         // [buf][64 keys x 8 chunks]   16 KB
    __shared__ uint4 Vs[2][512];         // [buf][64 dk x 8 key-chunks] 16 KB
    __shared__ uint4 Bls[2][1024];       // [buf][128 q-rows x 64 keys bf16] 32 KB
    __shared__ unsigned int Pb[4096];    // 4 waves x 32 rows x 64 keys bf16 16 KB

    const int t = threadIdx.x;
    const int lane = t & 63, w = t >> 6;
    const int g = lane >> 4, r15 = lane & 15;

    // XCD-aware remap (512 blocks, 64 per XCD chunk)
    const int p = blockIdx.x;
    const int logical = (p & 7) * 64 + (p >> 3);
    const int bh = logical >> 3, qt = logical & 7;
    const int b = bh >> 3, h = bh & 7;
    const int qbase = qt * 128 + w * 32;

    bf8 qf[2][2];
    #pragma unroll
    for (int u = 0; u < 2; ++u) {
        const unsigned short* qp = Qg + ((size_t)bh * LSEQ + qbase + u * 16 + r15) * DKD + g * 8;
        qf[u][0] = *(const bf8*)qp;
        qf[u][1] = *(const bf8*)(qp + 32);
    }

    float mrun[2] = {-1e30f, -1e30f}, lsum[2] = {0.f, 0.f};
    f4 oacc[2][4] = {};

    const int sr   = t >> 3;                   // 0..31 (K/V staging row)
    const int chs  = (t & 7) ^ (sr & 7);       // pre-swizzled source chunk
    const int brow = lane >> 3;                // 0..7  (bias staging row-in-group)
    const int bch  = (lane & 7) ^ brow;        // pre-swizzled bias source chunk
    unsigned short* Pw = (unsigned short*)(Pb + w * 1024);

    const size_t kBase = (size_t)bh * LSEQ * DKD;   // K rows
    const size_t vBase = (size_t)bh * DKD * LSEQ;   // V^T rows
    const unsigned short* bB = biasMb + ((size_t)b << 20);

    auto stage = [&](int buf, int key0) {
        const unsigned short* Kgp = Kg  + kBase + (size_t)(key0 + sr) * DKD + chs * 8;
        const unsigned short* Vgp = Vtg + vBase + (size_t)sr * LSEQ + key0 + chs * 8;
        unsigned short* Kl = (unsigned short*)Ks[buf] + (w * 8) * 64;
        unsigned short* Vl = (unsigned short*)Vs[buf] + (w * 8) * 64;
        gload16(Kgp, Kl);
        gload16(Kgp + (size_t)32 * DKD, Kl + 32 * 64);
        gload16(Vgp, Vl);
        gload16(Vgp + (size_t)32 * LSEQ, Vl + 32 * 64);
        unsigned short* Bl = (unsigned short*)Bls[buf] + w * 2048;   // 4KB/wave
        #pragma unroll
        for (int pp = 0; pp < 4; ++pp) {
            const unsigned short* Bgp = bB + (size_t)(qbase + pp * 8 + brow) * 1024
                                      + key0 + bch * 8;
            gload16(Bgp, Bl + pp * 512);
        }
    };

    stage(0, 0);
    __syncthreads();

    for (int kt = 0; kt < 16; ++kt) {
        const int cur = kt & 1;
        if (kt < 15) stage(cur ^ 1, (kt + 1) * 64);

        const char* Bw = (const char*)Bls[cur] + w * 4096;

        // S^T = K Q for both q-groups (K frags shared)
        f4 sacc[2][4] = {};
        __builtin_amdgcn_s_setprio(1);
        #pragma unroll
        for (int kk = 0; kk < 2; ++kk)
            #pragma unroll
            for (int m = 0; m < 4; ++m) {
                int row = m * 16 + r15;
                bf8 kf = *(const bf8*)&Ks[cur][row * 8 + ((kk * 4 + g) ^ (row & 7))];
                sacc[0][m] = __builtin_amdgcn_mfma_f32_16x16x32_bf16(kf, qf[0][kk], sacc[0][m], 0, 0, 0);
                sacc[1][m] = __builtin_amdgcn_mfma_f32_16x16x32_bf16(kf, qf[1][kk], sacc[1][m], 0, 0, 0);
            }
        __builtin_amdgcn_s_setprio(0);

        // softmax per q-group (per-lane over 16 keys + 2 shfl); bias from LDS
        #pragma unroll
        for (int u = 0; u < 2; ++u) {
            float s[16];
            float pmax = -1e30f;
            #pragma unroll
            for (int m = 0; m < 4; ++m) {
                int off = (u * 16 + r15) * 128 + ((m * 32 + g * 8) ^ ((r15 & 7) << 4));
                uint2 bv = *(const uint2*)(Bw + off);
                float b0 = __uint_as_float(bv.x << 16);
                float b1 = __uint_as_float(bv.x & 0xffff0000u);
                float b2 = __uint_as_float(bv.y << 16);
                float b3 = __uint_as_float(bv.y & 0xffff0000u);
                s[m * 4 + 0] = fmaf(sacc[u][m][0], 0.125f, b0);
                s[m * 4 + 1] = fmaf(sacc[u][m][1], 0.125f, b1);
                s[m * 4 + 2] = fmaf(sacc[u][m][2], 0.125f, b2);
                s[m * 4 + 3] = fmaf(sacc[u][m][3], 0.125f, b3);
                #pragma unroll
                for (int j = 0; j < 4; ++j) pmax = fmaxf(pmax, s[m * 4 + j]);
            }
            pmax = fmaxf(pmax, __shfl_xor(pmax, 16));
            pmax = fmaxf(pmax, __shfl_xor(pmax, 32));

            if (!__all(pmax <= mrun[u] + 8.f)) {     // defer-max (T13)
                float mnew = fmaxf(mrun[u], pmax);
                float scale = __expf(mrun[u] - mnew);
                lsum[u] *= scale;
                #pragma unroll
                for (int m = 0; m < 4; ++m)
                    #pragma unroll
                    for (int j = 0; j < 4; ++j) oacc[u][m][j] *= scale;
                mrun[u] = mnew;
            }

            float psum = 0.f;
            #pragma unroll
            for (int i = 0; i < 16; ++i) { s[i] = __expf(s[i] - mrun[u]); psum += s[i]; }
            psum += __shfl_xor(psum, 16);
            psum += __shfl_xor(psum, 32);
            lsum[u] += psum;

            // pack P -> per-wave LDS (bf16, XOR-swizzled), wave-private
            #pragma unroll
            for (int m = 0; m < 4; ++m) {
                uint2 pk;
                pk.x = cvtpk(s[m * 4 + 0], s[m * 4 + 1]);
                pk.y = cvtpk(s[m * 4 + 2], s[m * 4 + 3]);
                int off = ((u * 16 + r15) * 128 + m * 32 + g * 8) ^ ((r15 & 7) << 4);
                *(uint2*)((char*)Pw + off) = pk;
            }
        }

        // O^T += V^T P (V frags shared across q-groups)
        #pragma unroll
        for (int kk = 0; kk < 2; ++kk) {
            bf8 pf[2];
            #pragma unroll
            for (int u = 0; u < 2; ++u) {
                int off = ((u * 16 + r15) * 128 + kk * 64 + g * 16) ^ ((r15 & 7) << 4);
                pf[u] = *(const bf8*)((char*)Pw + off);
            }
            __builtin_amdgcn_s_setprio(1);
            #pragma unroll
            for (int m = 0; m < 4; ++m) {
                int row = m * 16 + r15;
                bf8 vf = *(const bf8*)&Vs[cur][row * 8 + ((kk * 4 + g) ^ (row & 7))];
                oacc[0][m] = __builtin_amdgcn_mfma_f32_16x16x32_bf16(vf, pf[0], oacc[0][m], 0, 0, 0);
                oacc[1][m] = __builtin_amdgcn_mfma_f32_16x16x32_bf16(vf, pf[1], oacc[1][m], 0, 0, 0);
            }
            __builtin_amdgcn_s_setprio(0);
        }
        __syncthreads();   // staged tile ready; all waves done with cur buffers
    }

    #pragma unroll
    for (int u = 0; u < 2; ++u) {
        float inv = 1.f / lsum[u];
        unsigned short* op = Ob + ((size_t)b * LSEQ + qbase + u * 16 + r15) * DMODEL + h * DKD;
        #pragma unroll
        for (int m = 0; m < 4; ++m) {
            ushort4 o4;
            o4.x = f2bf(oacc[u][m][0] * inv);
            o4.y = f2bf(oacc[u][m][1] * inv);
            o4.z = f2bf(oacc[u][m][2] * inv);
            o4.w = f2bf(oacc[u][m][3] * inv);
            *(ushort4*)(op + m * 16 + g * 4) = o4;
        }
    }
}

// ---------------------------------------------------------------------------
// LayerNorm (fp32), optional bf16 secondary output. One wave per row of 512.
// ---------------------------------------------------------------------------
__global__ __launch_bounds__(256) void ln_kernel(
    const float* __restrict__ in, const float* __restrict__ g,
    const float* __restrict__ bt, float* __restrict__ out,
    unsigned short* __restrict__ outb)
{
    const int row  = blockIdx.x * 4 + (threadIdx.x >> 6);
    const int lane = threadIdx.x & 63;
    const float* rp = in + (size_t)row * DMODEL + lane * 8;
    float4 x0 = *(const float4*)rp;
    float4 x1 = *(const float4*)(rp + 4);
    float xs[8] = {x0.x, x0.y, x0.z, x0.w, x1.x, x1.y, x1.z, x1.w};

    float sum = 0.f;
    #pragma unroll
    for (int i = 0; i < 8; ++i) sum += xs[i];
    #pragma unroll
    for (int off = 32; off; off >>= 1) sum += __shfl_xor(sum, off);
    float mu = sum * (1.f / 512.f);

    float vs = 0.f;
    #pragma unroll
    for (int i = 0; i < 8; ++i) { float d = xs[i] - mu; vs += d * d; }
    #pragma unroll
    for (int off = 32; off; off >>= 1) vs += __shfl_xor(vs, off);
    float rs = rsqrtf(vs * (1.f / 512.f) + 1e-5f);

    const float* gp = g  + lane * 8;
    const float* bp = bt + lane * 8;
    float4 g0 = *(const float4*)gp, g1 = *(const float4*)(gp + 4);
    float4 b0 = *(const float4*)bp, b1 = *(const float4*)(bp + 4);
    float gs[8] = {g0.x, g0.y, g0.z, g0.w, g1.x, g1.y, g1.z, g1.w};
    float bs[8] = {b0.x, b0.y, b0.z, b0.w, b1.x, b1.y, b1.z, b1.w};

    float res[8];
    #pragma unroll
    for (int i = 0; i < 8; ++i) res[i] = (xs[i] - mu) * rs * gs[i] + bs[i];

    float* op = out + (size_t)row * DMODEL + lane * 8;
    float4 r0 = {res[0], res[1], res[2], res[3]};
    float4 r1 = {res[4], res[5], res[6], res[7]};
    *(float4*)op       = r0;
    *(float4*)(op + 4) = r1;

    if (outb) {
        unsigned short* ob = outb + (size_t)row * DMODEL + lane * 8;
        ushort4 u0, u1;
        u0.x = f2bf(res[0]); u0.y = f2bf(res[1]); u0.z = f2bf(res[2]); u0.w = f2bf(res[3]);
        u1.x = f2bf(res[4]); u1.y = f2bf(res[5]); u1.z = f2bf(res[6]); u1.w = f2bf(res[7]);
        *(ushort4*)ob       = u0;
        *(ushort4*)(ob + 4) = u1;
    }
}

// ---------------------------------------------------------------------------
extern "C" void kernel_launch(void* const* d_in, const int* in_sizes, int n_in,
                              void* d_out, int out_size, void* d_ws, size_t ws_size,
                              hipStream_t stream)
{
    const float*         x    = (const float*)d_in[0];
    const unsigned char* mask = (const unsigned char*)d_in[1];
    const float*         bias = (const float*)d_in[2];
    const float* Wq = (const float*)d_in[3];
    const float* bq = (const float*)d_in[4];
    const float* Wk = (const float*)d_in[5];
    const float* bk = (const float*)d_in[6];
    const float* Wv = (const float*)d_in[7];
    const float* bv = (const float*)d_in[8];
    const float* Wo = (const float*)d_in[9];
    const float* bo = (const float*)d_in[10];
    const float* ln1g = (const float*)d_in[11];
    const float* ln1b = (const float*)d_in[12];
    const float* W1 = (const float*)d_in[13];
    const float* b1 = (const float*)d_in[14];
    const float* W2 = (const float*)d_in[15];
    const float* b2 = (const float*)d_in[16];
    const float* ln2g = (const float*)d_in[17];
    const float* ln2b = (const float*)d_in[18];

    char* W = (char*)d_ws;
    unsigned short* Qb   = (unsigned short*)(W);                 // 8 MB   [dead after attn]
    unsigned short* Kb   = (unsigned short*)(W + (8u << 20));    // 8 MB
    unsigned short* Vtb  = (unsigned short*)(W + (16u << 20));   // 8 MB
    unsigned short* Oball= (unsigned short*)(W + (24u << 20));   // 8 MB   [dead after out-proj]
    unsigned short* hb   = (unsigned short*)(W);                 // 32 MB  (reuses Q/K/Vt/O)
    unsigned short* biasMb=(unsigned short*)(W + (32u << 20));   // 16.8 MB [dead after attn]
    float*          y12  = (float*)(W + (32u << 20));            // 16 MB  (reuses biasMb lo)
    float*          x1   = (float*)(W + (49u << 20));            // 16 MB
    unsigned short* xb   = (unsigned short*)(W + (66u << 20));   // 8 MB
    unsigned short* x1b  = xb;                                   // reuse after QKV GEMM
    unsigned short* Wqkv = (unsigned short*)(W + (74u << 20));   // 1.5 MB
    unsigned short* Wot  = (unsigned short*)(W + (76u << 20));   // 0.5 MB
    unsigned short* W1t  = (unsigned short*)(W + (77u << 20));   // 2 MB
    unsigned short* W2t  = (unsigned short*)(W + (79u << 20));   // 2 MB
    float*          bqkv = (float*)(W + (81u << 20));            // 6 KB
    float*          outp = (float*)d_out;

    // prepass (3 launches)
    conv_bf16<<<dim3(4096), dim3(256), 0, stream>>>(x, xb, NBL * DMODEL);
    prep_weights<<<dim3(769), dim3(256), 0, stream>>>(
        Wq, Wk, Wv, Wo, W1, W2, bq, bk, bv, Wqkv, Wot, W1t, W2t, bqkv);
    biasmb_kernel<<<dim3(4096), dim3(256), 0, stream>>>(bias, mask, biasMb);

    // QKV fused projection, scatter to Q/K [bh,l,dk] and V^T [bh,dk,l]
    mfma_gemm<128><<<dim3(12, 64), dim3(256), 0, stream>>>(
        xb, Wqkv, bqkv, nullptr, nullptr, NBL, 1536, 512, 0, 2, Qb, Kb, Vtb);

    // attention (512 blocks x 128 q-rows)
    attn_mfma<<<dim3(512), dim3(256), 0, stream>>>(Qb, Kb, Vtb, biasMb, Oball);

    // out projection + residual(x) -> y1 (fp32); BN=64 -> 512 blocks
    mfma_gemm<64><<<dim3(8, 64), dim3(256), 0, stream>>>(
        Oball, Wot, bo, x, y12, NBL, 512, 512, 0, 0, nullptr, nullptr, nullptr);

    // LN1 -> x1 (fp32) + x1b (bf16)
    ln_kernel<<<dim3(NBL / 4), dim3(256), 0, stream>>>(y12, ln1g, ln1b, x1, x1b);

    // FFN1: relu(x1 @ W1 + b1) -> hb (bf16)
    mfma_gemm<128><<<dim3(16, 64), dim3(256), 0, stream>>>(
        x1b, W1t, b1, nullptr, hb, NBL, 2048, 512, 1, 1, nullptr, nullptr, nullptr);

    // FFN2: hb @ W2 + b2 + x1 -> y2 (fp32); BN=64 -> 512 blocks
    mfma_gemm<64><<<dim3(8, 64), dim3(256), 0, stream>>>(
        hb, W2t, b2, x1, y12, NBL, 512, 2048, 0, 0, nullptr, nullptr, nullptr);

    // LN2 -> output
    ln_kernel<<<dim3(NBL / 4), dim3(256), 0, stream>>>(y12, ln2g, ln2b, outp, nullptr);
}

// Round 12
// 327.771 us; speedup vs baseline: 1.1687x; 1.0005x over previous
//
#include <hip/hip_runtime.h>
#include <math.h>

#define NHEAD 8
#define DKD 64
#define DMODEL 512
#define LSEQ 1024
#define NBL 8192          // B*L

typedef __attribute__((ext_vector_type(8))) short bf8;   // 8 x bf16 (4 VGPRs)
typedef __attribute__((ext_vector_type(4))) float f4;    // MFMA accumulator

__device__ inline unsigned short f2bf(float f) {
    union { float f; unsigned u; } v; v.f = f;
    unsigned r = v.u + 0x7FFFu + ((v.u >> 16) & 1u);   // RNE
    return (unsigned short)(r >> 16);
}

// v_cvt_pk_bf16_f32: pack two fp32 -> two bf16 in one u32 (T12 recipe)
__device__ __forceinline__ unsigned cvtpk(float lo, float hi) {
    unsigned r;
    asm("v_cvt_pk_bf16_f32 %0, %1, %2" : "=v"(r) : "v"(lo), "v"(hi));
    return r;
}

// async global->LDS, 16B per lane. LDS dest = wave-uniform base + lane*16.
__device__ __forceinline__ void gload16(const void* g, void* l) {
    __builtin_amdgcn_global_load_lds(
        (const __attribute__((address_space(1))) unsigned int*)g,
        (__attribute__((address_space(3))) unsigned int*)l, 16, 0, 0);
}

// ---------------------------------------------------------------------------
// prepass: x->bf16, biasMb = bf16(bias + mask), weight transposes + bias concat
// all in ONE launch (8961 blocks) to cut launch count.
// ---------------------------------------------------------------------------
__device__ __forceinline__ void do_transpose(
    const float* __restrict__ W, unsigned short* __restrict__ Wt,
    int K, int N, int bx, int by)
{
    __shared__ float tile[64][65];
    const int k0 = by * 64, n0 = bx * 64;
    const int c = threadIdx.x & 63, r0 = (threadIdx.x >> 6) * 16;
    #pragma unroll
    for (int i = 0; i < 16; ++i)
        tile[r0 + i][c] = W[(size_t)(k0 + r0 + i) * N + n0 + c];
    __syncthreads();
    #pragma unroll
    for (int i = 0; i < 16; ++i)
        Wt[(size_t)(n0 + r0 + i) * K + k0 + c] = f2bf(tile[c][r0 + i]);
}

__global__ __launch_bounds__(256) void prep_all(
    const float* __restrict__ x, unsigned short* __restrict__ xb,
    const float* __restrict__ bias, const unsigned char* __restrict__ mask,
    unsigned short* __restrict__ biasMb,
    const float* __restrict__ Wq, const float* __restrict__ Wk,
    const float* __restrict__ Wv, const float* __restrict__ Wo,
    const float* __restrict__ W1, const float* __restrict__ W2,
    const float* __restrict__ bq, const float* __restrict__ bk,
    const float* __restrict__ bv,
    unsigned short* __restrict__ Wqkv, unsigned short* __restrict__ Wot,
    unsigned short* __restrict__ W1t, unsigned short* __restrict__ W2t,
    float* __restrict__ bqkv)
{
    const int j = blockIdx.x;
    if (j < 4096) {                              // x -> bf16
        int i = (j * 256 + threadIdx.x) * 4;
        float4 v = *(const float4*)(x + i);
        ushort4 o;
        o.x = f2bf(v.x); o.y = f2bf(v.y); o.z = f2bf(v.z); o.w = f2bf(v.w);
        *(ushort4*)(xb + i) = o;
    } else if (j < 8192) {                       // biasMb
        size_t flat = ((size_t)(j - 4096) * 256 + threadIdx.x) * 8;
        int b = (int)(flat >> 20);
        int k = (int)(flat & 1023);
        float4 v0 = *(const float4*)(bias + flat);
        float4 v1 = *(const float4*)(bias + flat + 4);
        uint2 mk = *(const uint2*)(mask + b * 1024 + k);
        float vs[8] = {v0.x, v0.y, v0.z, v0.w, v1.x, v1.y, v1.z, v1.w};
        unsigned mw[2] = {mk.x, mk.y};
        unsigned short os[8];
        #pragma unroll
        for (int q = 0; q < 8; ++q) {
            unsigned mb = (mw[q >> 2] >> ((q & 3) * 8)) & 0xffu;
            os[q] = f2bf(mb ? -1e30f : vs[q]);
        }
        uint4 pk;
        pk.x = (unsigned)os[0] | ((unsigned)os[1] << 16);
        pk.y = (unsigned)os[2] | ((unsigned)os[3] << 16);
        pk.z = (unsigned)os[4] | ((unsigned)os[5] << 16);
        pk.w = (unsigned)os[6] | ((unsigned)os[7] << 16);
        *(uint4*)(biasMb + flat) = pk;
    } else {                                     // weights
        int jj = j - 8192;
        if (jj < 256) {
            int which = jj >> 6, tt = jj & 63;
            const float* src = which == 0 ? Wq : which == 1 ? Wk : which == 2 ? Wv : Wo;
            unsigned short* dst = which == 0 ? Wqkv : which == 1 ? (Wqkv + 262144)
                                : which == 2 ? (Wqkv + 524288) : Wot;
            do_transpose(src, dst, 512, 512, tt & 7, tt >> 3);
        } else if (jj < 512) {
            int tt = jj - 256;
            do_transpose(W1, W1t, 512, 2048, tt & 31, tt >> 5);
        } else if (jj < 768) {
            int tt = jj - 512;
            do_transpose(W2, W2t, 2048, 512, tt & 7, tt >> 3);
        } else {
            for (int c = threadIdx.x; c < 1536; c += 256)
                bqkv[c] = c < 512 ? bq[c] : c < 1024 ? bk[c - 512] : bv[c - 1024];
        }
    }
}

// ---------------------------------------------------------------------------
// bf16 MFMA GEMM: C[M,N] = A[M,K] @ Bt[N,K]^T + bias. Tile 128 x BN, 4 waves.
// BK=64; 3-BUFFER COUNTED-VMCNT PIPELINE (T4): loads stay in flight across
// raw s_barriers; vmcnt(LOADS) counted (0 only on last iter). Prefetch
// distance = 2 tiles. global_load_lds staging, pre-swizzled source chunk,
// XOR-swizzled conflict-free ds_read_b128. XCD-bijective block remap (T1).
// outmode: 0 = fp32 [M,N] (+resid), 1 = bf16 [M,N] (+relu), 2 = QKV scatter
// ---------------------------------------------------------------------------
template<int BN>
__global__ __launch_bounds__(256) void mfma_gemm(
    const unsigned short* __restrict__ A, const unsigned short* __restrict__ Bt,
    const float* __restrict__ bias, const float* __restrict__ resid,
    void* __restrict__ outp, int M, int N, int K, int relu, int outmode,
    unsigned short* __restrict__ qs, unsigned short* __restrict__ ks,
    unsigned short* __restrict__ vts)
{
    __shared__ uint4 As[3][1024];       // [buf][128 rows x 8 chunks]  48 KB
    __shared__ uint4 Bs[3][BN * 8];     //                             24 KB (BN=64)
    constexpr int NB = BN / 32;         // acc cols per wave

    const int t = threadIdx.x;
    const int lane = t & 63, w = t >> 6;
    const int g = lane >> 4, r15 = lane & 15;
    const int wr = w >> 1, wc = w & 1;

    // T1: bijective XCD swizzle (nwg % 8 == 0 for all launches here)
    const int nwg  = gridDim.x * gridDim.y;
    const int flat = blockIdx.y * gridDim.x + blockIdx.x;
    const int swz  = (flat & 7) * (nwg >> 3) + (flat >> 3);
    const int bx   = swz % gridDim.x, by = swz / gridDim.x;
    const int rowBase = by * 128, colBase = bx * BN;

    f4 acc[4][NB] = {};

    const int r   = t >> 3;                    // w*8 + (lane>>3)
    const int chs = (t & 7) ^ (r & 7);         // pre-swizzled source chunk
    const unsigned short* Ag0 = A  + (size_t)(rowBase + r) * K + chs * 8;
    const unsigned short* Bg0 = Bt + (size_t)(colBase + r) * K + chs * 8;

    auto stage = [&](int buf, int k0) {
        unsigned short* Al = (unsigned short*)As[buf] + (w * 8) * 64;
        unsigned short* Bl = (unsigned short*)Bs[buf] + (w * 8) * 64;
        const unsigned short* Ag = Ag0 + k0;
        const unsigned short* Bg = Bg0 + k0;
        #pragma unroll
        for (int p = 0; p < 4; ++p)
            gload16(Ag + (size_t)(p * 32) * K, Al + p * 32 * 64);
        #pragma unroll
        for (int p = 0; p < NB; ++p)
            gload16(Bg + (size_t)(p * 32) * K, Bl + p * 32 * 64);
    };

    const int nst = K >> 6;                    // 8 or 32 (always >= 2)
    stage(0, 0);
    stage(1, 64);

    for (int it = 0; it < nst; ++it) {
        const int cur = it % 3;
        // counted wait: allow the newest stage (it+1) to stay in flight
        if (it + 1 < nst) {
            if constexpr (BN == 128) asm volatile("s_waitcnt vmcnt(8)" ::: "memory");
            else                     asm volatile("s_waitcnt vmcnt(6)" ::: "memory");
        } else {
            asm volatile("s_waitcnt vmcnt(0)" ::: "memory");
        }
        __builtin_amdgcn_sched_barrier(0);
        __builtin_amdgcn_s_barrier();          // all waves have tile `it`
        if (it + 2 < nst) stage((it + 2) % 3, (it + 2) << 6);

        #pragma unroll
        for (int kk = 0; kk < 2; ++kk) {
            bf8 af[4], bfr[NB];
            #pragma unroll
            for (int m = 0; m < 4; ++m) {
                int ra = wr * 64 + m * 16 + r15;
                af[m] = *(const bf8*)&As[cur][ra * 8 + ((kk * 4 + g) ^ (ra & 7))];
            }
            #pragma unroll
            for (int n = 0; n < NB; ++n) {
                int rb = wc * (BN / 2) + n * 16 + r15;
                bfr[n] = *(const bf8*)&Bs[cur][rb * 8 + ((kk * 4 + g) ^ (rb & 7))];
            }
            __builtin_amdgcn_s_setprio(1);
            #pragma unroll
            for (int m = 0; m < 4; ++m)
                #pragma unroll
                for (int n = 0; n < NB; ++n)
                    acc[m][n] = __builtin_amdgcn_mfma_f32_16x16x32_bf16(
                        af[m], bfr[n], acc[m][n], 0, 0, 0);
            __builtin_amdgcn_s_setprio(0);
        }
        __builtin_amdgcn_s_barrier();          // all waves done reading buf[cur]
    }

    #pragma unroll
    for (int m = 0; m < 4; ++m) {
        #pragma unroll
        for (int n = 0; n < NB; ++n) {
            int col = colBase + wc * (BN / 2) + n * 16 + r15;
            float bv = bias[col];
            #pragma unroll
            for (int rr = 0; rr < 4; ++rr) {
                int row = rowBase + wr * 64 + m * 16 + g * 4 + rr;
                float v = acc[m][n][rr] + bv;
                if (relu) v = fmaxf(v, 0.f);
                if (outmode == 0) {
                    size_t idx = (size_t)row * N + col;
                    if (resid) v += resid[idx];
                    ((float*)outp)[idx] = v;
                } else if (outmode == 1) {
                    ((unsigned short*)outp)[(size_t)row * N + col] = f2bf(v);
                } else {
                    int sel = col >> 9, hd = col & 511;
                    int h = hd >> 6, dk = hd & 63;
                    int b = row >> 10, l = row & 1023;
                    unsigned short bw = f2bf(v);
                    size_t bh = (size_t)(b * NHEAD + h);
                    if (sel == 0)      qs[(bh * LSEQ + l) * DKD + dk] = bw;
                    else if (sel == 1) ks[(bh * LSEQ + l) * DKD + dk] = bw;
                    else               vts[(bh * DKD + dk) * LSEQ + l] = bw;
                }
            }
        }
    }
}

// ---------------------------------------------------------------------------
// Flash attention v5. Block = 128 q-rows of one (b,h), 4 waves x 32 rows.
// Swapped QK^T (lane owns one q-row). K/V AND bf16 bias tiles double-buffered
// via global_load_lds (pre-swizzled source; XOR-swizzled LDS reads).
// Softmax reads bias from LDS (latency hidden by async staging). Low VGPR.
// setprio(1) around MFMA clusters (T5); defer-max (T13); cvt_pk P pack (T12).
// ---------------------------------------------------------------------------
__global__ __launch_bounds__(256) void attn_mfma(
    const unsigned short* __restrict__ Qg, const unsigned short* __restrict__ Kg,
    const unsigned short* __restrict__ Vtg, const unsigned short* __restrict__ biasMb,
    unsigned short* __restrict__ Ob)
{
    __shared__ uint4 Ks[2][512];         // [buf][64 keys x 8 chunks]   16 KB
    __shared__ uint4 Vs[2][512];         // [buf][64 dk x 8 key-chunks] 16 KB
    __shared__ uint4 Bls[2][1024];       // [buf][128 q-rows x 64 keys bf16] 32 KB
    __shared__ unsigned int Pb[4096];    // 4 waves x 32 rows x 64 keys bf16 16 KB

    const int t = threadIdx.x;
    const int lane = t & 63, w = t >> 6;
    const int g = lane >> 4, r15 = lane & 15;

    // XCD-aware remap (512 blocks, 64 per XCD chunk)
    const int p = blockIdx.x;
    const int logical = (p & 7) * 64 + (p >> 3);
    const int bh = logical >> 3, qt = logical & 7;
    const int b = bh >> 3, h = bh & 7;
    const int qbase = qt * 128 + w * 32;

    bf8 qf[2][2];
    #pragma unroll
    for (int u = 0; u < 2; ++u) {
        const unsigned short* qp = Qg + ((size_t)bh * LSEQ + qbase + u * 16 + r15) * DKD + g * 8;
        qf[u][0] = *(const bf8*)qp;
        qf[u][1] = *(const bf8*)(qp + 32);
    }

    float mrun[2] = {-1e30f, -1e30f}, lsum[2] = {0.f, 0.f};
    f4 oacc[2][4] = {};

    const int sr   = t >> 3;                   // 0..31 (K/V staging row)
    const int chs  = (t & 7) ^ (sr & 7);       // pre-swizzled source chunk
    const int brow = lane >> 3;                // 0..7  (bias staging row-in-group)
    const int bch  = (lane & 7) ^ brow;        // pre-swizzled bias source chunk
    unsigned short* Pw = (unsigned short*)(Pb + w * 1024);

    const size_t kBase = (size_t)bh * LSEQ * DKD;   // K rows
    const size_t vBase = (size_t)bh * DKD * LSEQ;   // V^T rows
    const unsigned short* bB = biasMb + ((size_t)b << 20);

    auto stage = [&](int buf, int key0) {
        const unsigned short* Kgp = Kg  + kBase + (size_t)(key0 + sr) * DKD + chs * 8;
        const unsigned short* Vgp = Vtg + vBase + (size_t)sr * LSEQ + key0 + chs * 8;
        unsigned short* Kl = (unsigned short*)Ks[buf] + (w * 8) * 64;
        unsigned short* Vl = (unsigned short*)Vs[buf] + (w * 8) * 64;
        gload16(Kgp, Kl);
        gload16(Kgp + (size_t)32 * DKD, Kl + 32 * 64);
        gload16(Vgp, Vl);
        gload16(Vgp + (size_t)32 * LSEQ, Vl + 32 * 64);
        unsigned short* Bl = (unsigned short*)Bls[buf] + w * 2048;   // 4KB/wave
        #pragma unroll
        for (int pp = 0; pp < 4; ++pp) {
            const unsigned short* Bgp = bB + (size_t)(qbase + pp * 8 + brow) * 1024
                                      + key0 + bch * 8;
            gload16(Bgp, Bl + pp * 512);
        }
    };

    stage(0, 0);
    __syncthreads();

    for (int kt = 0; kt < 16; ++kt) {
        const int cur = kt & 1;
        if (kt < 15) stage(cur ^ 1, (kt + 1) * 64);

        const char* Bw = (const char*)Bls[cur] + w * 4096;

        // S^T = K Q for both q-groups (K frags shared)
        f4 sacc[2][4] = {};
        __builtin_amdgcn_s_setprio(1);
        #pragma unroll
        for (int kk = 0; kk < 2; ++kk)
            #pragma unroll
            for (int m = 0; m < 4; ++m) {
                int row = m * 16 + r15;
                bf8 kf = *(const bf8*)&Ks[cur][row * 8 + ((kk * 4 + g) ^ (row & 7))];
                sacc[0][m] = __builtin_amdgcn_mfma_f32_16x16x32_bf16(kf, qf[0][kk], sacc[0][m], 0, 0, 0);
                sacc[1][m] = __builtin_amdgcn_mfma_f32_16x16x32_bf16(kf, qf[1][kk], sacc[1][m], 0, 0, 0);
            }
        __builtin_amdgcn_s_setprio(0);

        // softmax per q-group (per-lane over 16 keys + 2 shfl); bias from LDS
        #pragma unroll
        for (int u = 0; u < 2; ++u) {
            float s[16];
            float pmax = -1e30f;
            #pragma unroll
            for (int m = 0; m < 4; ++m) {
                int off = (u * 16 + r15) * 128 + ((m * 32 + g * 8) ^ ((r15 & 7) << 4));
                uint2 bv = *(const uint2*)(Bw + off);
                float b0 = __uint_as_float(bv.x << 16);
                float b1 = __uint_as_float(bv.x & 0xffff0000u);
                float b2 = __uint_as_float(bv.y << 16);
                float b3 = __uint_as_float(bv.y & 0xffff0000u);
                s[m * 4 + 0] = fmaf(sacc[u][m][0], 0.125f, b0);
                s[m * 4 + 1] = fmaf(sacc[u][m][1], 0.125f, b1);
                s[m * 4 + 2] = fmaf(sacc[u][m][2], 0.125f, b2);
                s[m * 4 + 3] = fmaf(sacc[u][m][3], 0.125f, b3);
                #pragma unroll
                for (int j = 0; j < 4; ++j) pmax = fmaxf(pmax, s[m * 4 + j]);
            }
            pmax = fmaxf(pmax, __shfl_xor(pmax, 16));
            pmax = fmaxf(pmax, __shfl_xor(pmax, 32));

            if (!__all(pmax <= mrun[u] + 8.f)) {     // defer-max (T13)
                float mnew = fmaxf(mrun[u], pmax);
                float scale = __expf(mrun[u] - mnew);
                lsum[u] *= scale;
                #pragma unroll
                for (int m = 0; m < 4; ++m)
                    #pragma unroll
                    for (int j = 0; j < 4; ++j) oacc[u][m][j] *= scale;
                mrun[u] = mnew;
            }

            float psum = 0.f;
            #pragma unroll
            for (int i = 0; i < 16; ++i) { s[i] = __expf(s[i] - mrun[u]); psum += s[i]; }
            psum += __shfl_xor(psum, 16);
            psum += __shfl_xor(psum, 32);
            lsum[u] += psum;

            // pack P -> per-wave LDS (bf16, XOR-swizzled), wave-private
            #pragma unroll
            for (int m = 0; m < 4; ++m) {
                uint2 pk;
                pk.x = cvtpk(s[m * 4 + 0], s[m * 4 + 1]);
                pk.y = cvtpk(s[m * 4 + 2], s[m * 4 + 3]);
                int off = ((u * 16 + r15) * 128 + m * 32 + g * 8) ^ ((r15 & 7) << 4);
                *(uint2*)((char*)Pw + off) = pk;
            }
        }

        // O^T += V^T P (V frags shared across q-groups)
        #pragma unroll
        for (int kk = 0; kk < 2; ++kk) {
            bf8 pf[2];
            #pragma unroll
            for (int u = 0; u < 2; ++u) {
                int off = ((u * 16 + r15) * 128 + kk * 64 + g * 16) ^ ((r15 & 7) << 4);
                pf[u] = *(const bf8*)((char*)Pw + off);
            }
            __builtin_amdgcn_s_setprio(1);
            #pragma unroll
            for (int m = 0; m < 4; ++m) {
                int row = m * 16 + r15;
                bf8 vf = *(const bf8*)&Vs[cur][row * 8 + ((kk * 4 + g) ^ (row & 7))];
                oacc[0][m] = __builtin_amdgcn_mfma_f32_16x16x32_bf16(vf, pf[0], oacc[0][m], 0, 0, 0);
                oacc[1][m] = __builtin_amdgcn_mfma_f32_16x16x32_bf16(vf, pf[1], oacc[1][m], 0, 0, 0);
            }
            __builtin_amdgcn_s_setprio(0);
        }
        __syncthreads();   // staged tile ready; all waves done with cur buffers
    }

    #pragma unroll
    for (int u = 0; u < 2; ++u) {
        float inv = 1.f / lsum[u];
        unsigned short* op = Ob + ((size_t)b * LSEQ + qbase + u * 16 + r15) * DMODEL + h * DKD;
        #pragma unroll
        for (int m = 0; m < 4; ++m) {
            ushort4 o4;
            o4.x = f2bf(oacc[u][m][0] * inv);
            o4.y = f2bf(oacc[u][m][1] * inv);
            o4.z = f2bf(oacc[u][m][2] * inv);
            o4.w = f2bf(oacc[u][m][3] * inv);
            *(ushort4*)(op + m * 16 + g * 4) = o4;
        }
    }
}

// ---------------------------------------------------------------------------
// LayerNorm (fp32), optional bf16 secondary output. One wave per row of 512.
// ---------------------------------------------------------------------------
__global__ __launch_bounds__(256) void ln_kernel(
    const float* __restrict__ in, const float* __restrict__ g,
    const float* __restrict__ bt, float* __restrict__ out,
    unsigned short* __restrict__ outb)
{
    const int row  = blockIdx.x * 4 + (threadIdx.x >> 6);
    const int lane = threadIdx.x & 63;
    const float* rp = in + (size_t)row * DMODEL + lane * 8;
    float4 x0 = *(const float4*)rp;
    float4 x1 = *(const float4*)(rp + 4);
    float xs[8] = {x0.x, x0.y, x0.z, x0.w, x1.x, x1.y, x1.z, x1.w};

    float sum = 0.f;
    #pragma unroll
    for (int i = 0; i < 8; ++i) sum += xs[i];
    #pragma unroll
    for (int off = 32; off; off >>= 1) sum += __shfl_xor(sum, off);
    float mu = sum * (1.f / 512.f);

    float vs = 0.f;
    #pragma unroll
    for (int i = 0; i < 8; ++i) { float d = xs[i] - mu; vs += d * d; }
    #pragma unroll
    for (int off = 32; off; off >>= 1) vs += __shfl_xor(vs, off);
    float rs = rsqrtf(vs * (1.f / 512.f) + 1e-5f);

    const float* gp = g  + lane * 8;
    const float* bp = bt + lane * 8;
    float4 g0 = *(const float4*)gp, g1 = *(const float4*)(gp + 4);
    float4 b0 = *(const float4*)bp, b1 = *(const float4*)(bp + 4);
    float gs[8] = {g0.x, g0.y, g0.z, g0.w, g1.x, g1.y, g1.z, g1.w};
    float bs[8] = {b0.x, b0.y, b0.z, b0.w, b1.x, b1.y, b1.z, b1.w};

    float res[8];
    #pragma unroll
    for (int i = 0; i < 8; ++i) res[i] = (xs[i] - mu) * rs * gs[i] + bs[i];

    float* op = out + (size_t)row * DMODEL + lane * 8;
    float4 r0 = {res[0], res[1], res[2], res[3]};
    float4 r1 = {res[4], res[5], res[6], res[7]};
    *(float4*)op       = r0;
    *(float4*)(op + 4) = r1;

    if (outb) {
        unsigned short* ob = outb + (size_t)row * DMODEL + lane * 8;
        ushort4 u0, u1;
        u0.x = f2bf(res[0]); u0.y = f2bf(res[1]); u0.z = f2bf(res[2]); u0.w = f2bf(res[3]);
        u1.x = f2bf(res[4]); u1.y = f2bf(res[5]); u1.z = f2bf(res[6]); u1.w = f2bf(res[7]);
        *(ushort4*)ob       = u0;
        *(ushort4*)(ob + 4) = u1;
    }
}

// ---------------------------------------------------------------------------
extern "C" void kernel_launch(void* const* d_in, const int* in_sizes, int n_in,
                              void* d_out, int out_size, void* d_ws, size_t ws_size,
                              hipStream_t stream)
{
    const float*         x    = (const float*)d_in[0];
    const unsigned char* mask = (const unsigned char*)d_in[1];
    const float*         bias = (const float*)d_in[2];
    const float* Wq = (const float*)d_in[3];
    const float* bq = (const float*)d_in[4];
    const float* Wk = (const float*)d_in[5];
    const float* bk = (const float*)d_in[6];
    const float* Wv = (const float*)d_in[7];
    const float* bv = (const float*)d_in[8];
    const float* Wo = (const float*)d_in[9];
    const float* bo = (const float*)d_in[10];
    const float* ln1g = (const float*)d_in[11];
    const float* ln1b = (const float*)d_in[12];
    const float* W1 = (const float*)d_in[13];
    const float* b1 = (const float*)d_in[14];
    const float* W2 = (const float*)d_in[15];
    const float* b2 = (const float*)d_in[16];
    const float* ln2g = (const float*)d_in[17];
    const float* ln2b = (const float*)d_in[18];

    char* W = (char*)d_ws;
    unsigned short* Qb   = (unsigned short*)(W);                 // 8 MB   [dead after attn]
    unsigned short* Kb   = (unsigned short*)(W + (8u << 20));    // 8 MB
    unsigned short* Vtb  = (unsigned short*)(W + (16u << 20));   // 8 MB
    unsigned short* Oball= (unsigned short*)(W + (24u << 20));   // 8 MB   [dead after out-proj]
    unsigned short* hb   = (unsigned short*)(W);                 // 32 MB  (reuses Q/K/Vt/O)
    unsigned short* biasMb=(unsigned short*)(W + (32u << 20));   // 16.8 MB [dead after attn]
    float*          y12  = (float*)(W + (32u << 20));            // 16 MB  (reuses biasMb lo)
    float*          x1   = (float*)(W + (49u << 20));            // 16 MB
    unsigned short* xb   = (unsigned short*)(W + (66u << 20));   // 8 MB
    unsigned short* x1b  = xb;                                   // reuse after QKV GEMM
    unsigned short* Wqkv = (unsigned short*)(W + (74u << 20));   // 1.5 MB
    unsigned short* Wot  = (unsigned short*)(W + (76u << 20));   // 0.5 MB
    unsigned short* W1t  = (unsigned short*)(W + (77u << 20));   // 2 MB
    unsigned short* W2t  = (unsigned short*)(W + (79u << 20));   // 2 MB
    float*          bqkv = (float*)(W + (81u << 20));            // 6 KB
    float*          outp = (float*)d_out;

    // prepass (1 launch)
    prep_all<<<dim3(8961), dim3(256), 0, stream>>>(
        x, xb, bias, mask, biasMb, Wq, Wk, Wv, Wo, W1, W2,
        bq, bk, bv, Wqkv, Wot, W1t, W2t, bqkv);

    // QKV fused projection, scatter to Q/K [bh,l,dk] and V^T [bh,dk,l]
    mfma_gemm<64><<<dim3(24, 64), dim3(256), 0, stream>>>(
        xb, Wqkv, bqkv, nullptr, nullptr, NBL, 1536, 512, 0, 2, Qb, Kb, Vtb);

    // attention (512 blocks x 128 q-rows)
    attn_mfma<<<dim3(512), dim3(256), 0, stream>>>(Qb, Kb, Vtb, biasMb, Oball);

    // out projection + residual(x) -> y1 (fp32)
    mfma_gemm<64><<<dim3(8, 64), dim3(256), 0, stream>>>(
        Oball, Wot, bo, x, y12, NBL, 512, 512, 0, 0, nullptr, nullptr, nullptr);

    // LN1 -> x1 (fp32) + x1b (bf16)
    ln_kernel<<<dim3(NBL / 4), dim3(256), 0, stream>>>(y12, ln1g, ln1b, x1, x1b);

    // FFN1: relu(x1 @ W1 + b1) -> hb (bf16)
    mfma_gemm<64><<<dim3(32, 64), dim3(256), 0, stream>>>(
        x1b, W1t, b1, nullptr, hb, NBL, 2048, 512, 1, 1, nullptr, nullptr, nullptr);

    // FFN2: hb @ W2 + b2 + x1 -> y2 (fp32)
    mfma_gemm<64><<<dim3(8, 64), dim3(256), 0, stream>>>(
        hb, W2t, b2, x1, y12, NBL, 512, 2048, 0, 0, nullptr, nullptr, nullptr);

    // LN2 -> output
    ln_kernel<<<dim3(NBL / 4), dim3(256), 0, stream>>>(y12, ln2g, ln2b, outp, nullptr);
}